// Round 1
// baseline (1191.746 us; speedup 1.0000x reference)
//
#include <hip/hip_runtime.h>
#include <hip/hip_bf16.h>
#include <math.h>

#define B_ 32
#define N_ 128
#define L_ 1024
#define DD_ 256
#define TD_ 1280
#define HID_ 512
#define H_ 8
#define HD_ 64
#define LT 32
#define HB_ 256

// ws layout (float offsets)
#define WS_T 0
#define WS_D (WS_T + (size_t)B_*L_*HID_)          // 16777216
#define WS_RM (WS_D + (size_t)B_*N_*HID_)         // 18874368
#define WS_RZ (WS_RM + (size_t)H_*B_*N_)          // +32768
#define WS_CNT (WS_RZ + (size_t)H_*B_*N_)         // 18939904 (ints live here)

// ---------------------------------------------------------------------------
// K0: per-batch valid counts. Detect int32 vs packed-bool masks at runtime:
// first element is always True (lengths >= max/2), so int32 gives 1 and
// byte-packed bool gives 0x01010101.
// ---------------------------------------------------------------------------
__global__ __launch_bounds__(256) void count_kernel(const int* __restrict__ dmask,
                                                    const int* __restrict__ tmask,
                                                    int* __restrict__ cnts) {
  __shared__ int red[256];
  const int b = blockIdx.x, tid = threadIdx.x;
  const bool dint = (dmask[0] == 1);
  const bool tint = (tmask[0] == 1);
  int s = 0;
  if (dint) {
    for (int i = tid; i < N_; i += 256) s += (dmask[(size_t)b*N_ + i] != 0);
  } else {
    const unsigned char* p = (const unsigned char*)dmask;
    for (int i = tid; i < N_; i += 256) s += (p[(size_t)b*N_ + i] != 0);
  }
  red[tid] = s; __syncthreads();
  for (int off = 128; off > 0; off >>= 1) { if (tid < off) red[tid] += red[tid+off]; __syncthreads(); }
  if (tid == 0) cnts[b*2] = red[0];
  __syncthreads();
  s = 0;
  if (tint) {
    for (int i = tid; i < L_; i += 256) s += (tmask[(size_t)b*L_ + i] != 0);
  } else {
    const unsigned char* p = (const unsigned char*)tmask;
    for (int i = tid; i < L_; i += 256) s += (p[(size_t)b*L_ + i] != 0);
  }
  red[tid] = s; __syncthreads();
  for (int off = 128; off > 0; off >>= 1) { if (tid < off) red[tid] += red[tid+off]; __syncthreads(); }
  if (tid == 0) cnts[b*2+1] = red[0];
}

// ---------------------------------------------------------------------------
// K1: C = A(MxK) @ W(KxN) + bias, fp32. 128x128 tile, BK=8, 256 threads,
// 8x8 per thread split as 4 quads spaced 64 apart (bank-conflict-free LDS).
// M % 128 == 0, K % 8 == 0, N % 128 == 0 (holds for both projections).
// ---------------------------------------------------------------------------
__global__ __launch_bounds__(256) void gemm_bias_kernel(
    const float* __restrict__ A, const float* __restrict__ W,
    const float* __restrict__ bias, float* __restrict__ C,
    int M, int K, int Nd) {
  __shared__ float As[8][132];
  __shared__ float Bs[8][132];
  const int tid = threadIdx.x;
  const int m0 = blockIdx.y * 128, n0 = blockIdx.x * 128;
  const int lr = tid >> 1, lc = (tid & 1) * 4;   // A staging: row, k-chunk
  const int wr = tid >> 5, wc = (tid & 31) * 4;  // W staging: k-row, col-chunk
  const int tm = (tid >> 4) * 4, tn = (tid & 15) * 4;

  float acc[2][2][4][4];
#pragma unroll
  for (int a = 0; a < 2; a++)
#pragma unroll
    for (int bq = 0; bq < 2; bq++)
#pragma unroll
      for (int i = 0; i < 4; i++)
#pragma unroll
        for (int j = 0; j < 4; j++) acc[a][bq][i][j] = 0.f;

  const float* Aptr = A + (size_t)(m0 + lr) * K + lc;
  const float* Wptr = W + (size_t)wr * Nd + n0 + wc;

  for (int k0 = 0; k0 < K; k0 += 8) {
    float4 a4 = *(const float4*)(Aptr + k0);
    float4 w4 = *(const float4*)(Wptr + (size_t)k0 * Nd);
    __syncthreads();
    As[lc+0][lr] = a4.x; As[lc+1][lr] = a4.y; As[lc+2][lr] = a4.z; As[lc+3][lr] = a4.w;
    *(float4*)&Bs[wr][wc] = w4;
    __syncthreads();
#pragma unroll
    for (int kk = 0; kk < 8; kk++) {
      float4 a0 = *(const float4*)&As[kk][tm];
      float4 a1 = *(const float4*)&As[kk][tm + 64];
      float4 b0 = *(const float4*)&Bs[kk][tn];
      float4 b1 = *(const float4*)&Bs[kk][tn + 64];
      const float av0[4] = {a0.x, a0.y, a0.z, a0.w};
      const float av1[4] = {a1.x, a1.y, a1.z, a1.w};
      const float bv0[4] = {b0.x, b0.y, b0.z, b0.w};
      const float bv1[4] = {b1.x, b1.y, b1.z, b1.w};
#pragma unroll
      for (int i = 0; i < 4; i++)
#pragma unroll
        for (int j = 0; j < 4; j++) {
          acc[0][0][i][j] += av0[i] * bv0[j];
          acc[0][1][i][j] += av0[i] * bv1[j];
          acc[1][0][i][j] += av1[i] * bv0[j];
          acc[1][1][i][j] += av1[i] * bv1[j];
        }
    }
  }
  float4 bias0 = *(const float4*)&bias[n0 + tn];
  float4 bias1 = *(const float4*)&bias[n0 + tn + 64];
  const float bb0[4] = {bias0.x, bias0.y, bias0.z, bias0.w};
  const float bb1[4] = {bias1.x, bias1.y, bias1.z, bias1.w};
#pragma unroll
  for (int mh = 0; mh < 2; mh++)
#pragma unroll
    for (int i = 0; i < 4; i++) {
      const int row = m0 + mh * 64 + tm + i;
      float* cp = C + (size_t)row * Nd + n0;
      float4 o0, o1;
      o0.x = acc[mh][0][i][0] + bb0[0]; o0.y = acc[mh][0][i][1] + bb0[1];
      o0.z = acc[mh][0][i][2] + bb0[2]; o0.w = acc[mh][0][i][3] + bb0[3];
      o1.x = acc[mh][1][i][0] + bb1[0]; o1.y = acc[mh][1][i][1] + bb1[1];
      o1.z = acc[mh][1][i][2] + bb1[2]; o1.w = acc[mh][1][i][3] + bb1[3];
      *(float4*)(cp + tn) = o0;
      *(float4*)(cp + tn + 64) = o1;
    }
}

// ---------------------------------------------------------------------------
// Shared device helpers for the attention passes.
// LDS strides: dw_s/th_s/wbT/dbuf stride 68 (float4-aligned, conflict-light),
// S_s stride 33 (odd: row AND column scalar walks conflict-free).
// ---------------------------------------------------------------------------
__device__ __forceinline__ void compute_dW(const float* __restrict__ dproj,
                                           const float* __restrict__ Wb,
                                           float* __restrict__ dw_s,   // [128*68]
                                           float* __restrict__ wbT,    // [64*68]
                                           float* __restrict__ dbuf,   // [32*68]
                                           int h, int b, int tid) {
  // load Wb[h] transposed: wbT[e][k] = Wb[h][k][e]
  {
    const int r = tid >> 2;          // k index 0..63
    const int cc = tid & 3;
    const float* wb = Wb + (size_t)h * (HD_ * HD_) + (size_t)r * HD_;
#pragma unroll
    for (int c = 0; c < 4; c++) {
      const int e0 = (cc + 4 * c) * 4;
      float4 v = *(const float4*)(wb + e0);
      wbT[(e0+0)*68 + r] = v.x; wbT[(e0+1)*68 + r] = v.y;
      wbT[(e0+2)*68 + r] = v.z; wbT[(e0+3)*68 + r] = v.w;
    }
  }
  __syncthreads();
  const int r = tid >> 3, cc = tid & 7;
  const int e = tid & 63, ng = tid >> 6;
  for (int ch = 0; ch < 4; ch++) {
    const float* dp = dproj + ((size_t)(b * N_ + ch * 32 + r)) * HID_ + h * HD_;
    float4 v0 = *(const float4*)(dp + cc * 4);
    float4 v1 = *(const float4*)(dp + cc * 4 + 32);
    __syncthreads();   // previous chunk's compute done before overwrite
    *(float4*)&dbuf[r * 68 + cc * 4] = v0;
    *(float4*)&dbuf[r * 68 + cc * 4 + 32] = v1;
    __syncthreads();
    float accv[8];
#pragma unroll
    for (int i = 0; i < 8; i++) accv[i] = 0.f;
    for (int k4 = 0; k4 < 16; k4++) {
      float4 wv = *(const float4*)&wbT[e * 68 + k4 * 4];
#pragma unroll
      for (int i = 0; i < 8; i++) {
        float4 dv = *(const float4*)&dbuf[(ng + 4 * i) * 68 + k4 * 4];
        accv[i] += dv.x * wv.x + dv.y * wv.y + dv.z * wv.z + dv.w * wv.w;
      }
    }
#pragma unroll
    for (int i = 0; i < 8; i++) dw_s[(ch * 32 + ng + 4 * i) * 68 + e] = accv[i];
  }
  __syncthreads();
}

__device__ __forceinline__ void load_th_tile(const float* __restrict__ tproj,
                                             float* __restrict__ th_s,
                                             int b, int h, int l0, int tid) {
  const int r = tid >> 3, cc = tid & 7;
  const float* tp = tproj + ((size_t)(b * L_ + l0 + r)) * HID_ + h * HD_;
  float4 v0 = *(const float4*)(tp + cc * 4);
  float4 v1 = *(const float4*)(tp + cc * 4 + 32);
  __syncthreads();   // previous tile fully consumed
  *(float4*)&th_s[r * 68 + cc * 4] = v0;
  *(float4*)&th_s[r * 68 + cc * 4 + 32] = v1;
}

__device__ __forceinline__ void compute_S(const float* __restrict__ dw_s,
                                          const float* __restrict__ th_s,
                                          float* __restrict__ S_s, int tid) {
  const int lg = tid & 7, ng = tid >> 3;
  float acc[4][4];
#pragma unroll
  for (int i = 0; i < 4; i++)
#pragma unroll
    for (int j = 0; j < 4; j++) acc[i][j] = 0.f;
  for (int k4 = 0; k4 < 16; k4++) {
    float4 tv[4], dv[4];
#pragma unroll
    for (int j = 0; j < 4; j++) tv[j] = *(const float4*)&th_s[(lg + 8 * j) * 68 + k4 * 4];
#pragma unroll
    for (int i = 0; i < 4; i++) dv[i] = *(const float4*)&dw_s[(ng + 32 * i) * 68 + k4 * 4];
#pragma unroll
    for (int i = 0; i < 4; i++)
#pragma unroll
      for (int j = 0; j < 4; j++)
        acc[i][j] += dv[i].x * tv[j].x + dv[i].y * tv[j].y + dv[i].z * tv[j].z + dv[i].w * tv[j].w;
  }
#pragma unroll
  for (int i = 0; i < 4; i++)
#pragma unroll
    for (int j = 0; j < 4; j++) S_s[(ng + 32 * i) * 33 + lg + 8 * j] = acc[i][j];
}

// ---------------------------------------------------------------------------
// K3a: per (h,b): S tiles -> column softmax stats (complete per tile since a
// full column of N=128 fits) -> accumulate w[n] = sum_l P_t[n,l]; online row
// softmax stats (m,Z per n, thread-resident registers). Epilogue: ctx_t.
// ---------------------------------------------------------------------------
__global__ __launch_bounds__(256) void attn_pass1(
    const float* __restrict__ tproj, const float* __restrict__ dproj,
    const float* __restrict__ Wb, const int* __restrict__ cnts,
    float* __restrict__ rowm, float* __restrict__ rowz,
    float* __restrict__ outp) {
  __shared__ float dw_s[128 * 68];
  __shared__ float bufB[6528];          // phase0: wbT[4352]+dbuf[2176]; phase1: th[2176]+S[4224]
  __shared__ float cm_s[32], ics_s[32], colpart[256], wv_s[128];
  const int tid = threadIdx.x;
  const int hb = blockIdx.x;
  const int h = hb >> 5, b = hb & 31;

  compute_dW(dproj, Wb, dw_s, bufB, bufB + 64 * 68, h, b, tid);

  float* th_s = bufB;
  float* S_s = bufB + 32 * 68;
  const int ncnt = cnts[b * 2];
  const int lcnt = cnts[b * 2 + 1];
  const int ntiles = (lcnt + LT - 1) / LT;

  float m_r = -INFINITY, z_r = 0.f, w_r = 0.f;   // owned by thread n = tid (<128)

  for (int tI = 0; tI < ntiles; tI++) {
    const int l0 = tI * LT;
    const int lv = min(LT, lcnt - l0);
    load_th_tile(tproj, th_s, b, h, l0, tid);
    __syncthreads();
    compute_S(dw_s, th_s, S_s, tid);
    __syncthreads();
    // column max partials
    {
      const int l = tid & 31, q = tid >> 5;
      float pm = -INFINITY;
      if (l < lv) {
        const int nbeg = q * 16, nend = min(nbeg + 16, ncnt);
        for (int n = nbeg; n < nend; n++) pm = fmaxf(pm, S_s[n * 33 + l]);
      }
      colpart[q * 32 + l] = pm;
    }
    __syncthreads();
    if (tid < lv) {
      float cmax = colpart[tid];
#pragma unroll
      for (int q = 1; q < 8; q++) cmax = fmaxf(cmax, colpart[q * 32 + tid]);
      cm_s[tid] = cmax;
    }
    __syncthreads();
    // column expsum partials
    {
      const int l = tid & 31, q = tid >> 5;
      float ps = 0.f;
      if (l < lv) {
        const float cmax = cm_s[l];
        const int nbeg = q * 16, nend = min(nbeg + 16, ncnt);
        for (int n = nbeg; n < nend; n++) ps += __expf(S_s[n * 33 + l] - cmax);
      }
      colpart[q * 32 + l] = ps;
    }
    __syncthreads();
    if (tid < lv) {
      float cs = 0.f;
#pragma unroll
      for (int q = 0; q < 8; q++) cs += colpart[q * 32 + tid];
      ics_s[tid] = 1.f / cs;
    }
    __syncthreads();
    // row pass: online (m, Z) + w accumulation, thread n = tid
    if (tid < ncnt) {
      const int n = tid;
      float tmax = -INFINITY;
      for (int l = 0; l < lv; l++) tmax = fmaxf(tmax, S_s[n * 33 + l]);
      const float mnew = fmaxf(m_r, tmax);
      z_r *= __expf(m_r - mnew);       // exp(-inf)=0 on first tile
      for (int l = 0; l < lv; l++) {
        const float s = S_s[n * 33 + l];
        z_r += __expf(s - mnew);
        w_r += __expf(s - cm_s[l]) * ics_s[l];
      }
      m_r = mnew;
    }
    __syncthreads();
  }
  if (tid < 128) wv_s[tid] = (tid < ncnt) ? w_r : 0.f;
  if (tid < ncnt) {
    rowm[(size_t)hb * 128 + tid] = m_r;
    rowz[(size_t)hb * 128 + tid] = z_r;
  }
  __syncthreads();
  if (tid < 64) {
    float a = 0.f;
    const float* dp = dproj + (size_t)b * N_ * HID_ + h * HD_ + tid;
    for (int n = 0; n < ncnt; n++) a += wv_s[n] * dp[(size_t)n * HID_];
    outp[(size_t)b * (2 * HID_) + HID_ + h * HD_ + tid] = a / (float)lcnt;
  }
}

// ---------------------------------------------------------------------------
// K3b: per (h,b): recompute S tiles; v[l] = sum_n exp(S-m[n])/Z[n];
// ctx_d[e] = sum_l v[l]*th[l][e] / ncnt.
// ---------------------------------------------------------------------------
__global__ __launch_bounds__(256) void attn_pass2(
    const float* __restrict__ tproj, const float* __restrict__ dproj,
    const float* __restrict__ Wb, const int* __restrict__ cnts,
    const float* __restrict__ rowm, const float* __restrict__ rowz,
    float* __restrict__ outp) {
  __shared__ float dw_s[128 * 68];
  __shared__ float bufB[6528];
  __shared__ float rm_s[128], riz_s[128], vpart[256], v_s[32];
  const int tid = threadIdx.x;
  const int hb = blockIdx.x;
  const int h = hb >> 5, b = hb & 31;

  compute_dW(dproj, Wb, dw_s, bufB, bufB + 64 * 68, h, b, tid);

  float* th_s = bufB;
  float* S_s = bufB + 32 * 68;
  const int ncnt = cnts[b * 2];
  const int lcnt = cnts[b * 2 + 1];
  const int ntiles = (lcnt + LT - 1) / LT;

  if (tid < 128 && tid < ncnt) {
    rm_s[tid] = rowm[(size_t)hb * 128 + tid];
    riz_s[tid] = 1.f / rowz[(size_t)hb * 128 + tid];
  }
  __syncthreads();

  float ctx = 0.f;   // thread e = tid (<64)
  for (int tI = 0; tI < ntiles; tI++) {
    const int l0 = tI * LT;
    const int lv = min(LT, lcnt - l0);
    load_th_tile(tproj, th_s, b, h, l0, tid);
    __syncthreads();
    compute_S(dw_s, th_s, S_s, tid);
    __syncthreads();
    {
      const int l = tid & 31, q = tid >> 5;
      float vp = 0.f;
      if (l < lv) {
        const int nbeg = q * 16, nend = min(nbeg + 16, ncnt);
        for (int n = nbeg; n < nend; n++)
          vp += __expf(S_s[n * 33 + l] - rm_s[n]) * riz_s[n];
      }
      vpart[q * 32 + l] = vp;
    }
    __syncthreads();
    if (tid < lv) {
      float v = 0.f;
#pragma unroll
      for (int q = 0; q < 8; q++) v += vpart[q * 32 + tid];
      v_s[tid] = v;
    }
    __syncthreads();
    if (tid < 64) {
      for (int l = 0; l < lv; l++) ctx += v_s[l] * th_s[l * 68 + tid];
    }
    __syncthreads();
  }
  if (tid < 64) {
    outp[(size_t)b * (2 * HID_) + h * HD_ + tid] = ctx / (float)ncnt;
  }
}

// ---------------------------------------------------------------------------
extern "C" void kernel_launch(void* const* d_in, const int* in_sizes, int n_in,
                              void* d_out, int out_size, void* d_ws, size_t ws_size,
                              hipStream_t stream) {
  const float* drug = (const float*)d_in[0];
  const int* dmask = (const int*)d_in[1];
  const float* tseq = (const float*)d_in[2];
  const int* tmask = (const int*)d_in[3];
  const float* Wd = (const float*)d_in[4];
  const float* bd = (const float*)d_in[5];
  const float* Wt = (const float*)d_in[6];
  const float* bt = (const float*)d_in[7];
  const float* Wb = (const float*)d_in[8];
  float* out = (float*)d_out;
  float* ws = (float*)d_ws;

  float* t = ws + WS_T;          // (B*L, 512)
  float* dp = ws + WS_D;         // (B*N, 512)
  float* rm = ws + WS_RM;        // (H*B, 128)
  float* rz = ws + WS_RZ;        // (H*B, 128)
  int* cnts = (int*)(ws + WS_CNT);

  count_kernel<<<B_, 256, 0, stream>>>(dmask, tmask, cnts);
  gemm_bias_kernel<<<dim3(HID_ / 128, (B_ * L_) / 128), 256, 0, stream>>>(
      tseq, Wt, bt, t, B_ * L_, TD_, HID_);
  gemm_bias_kernel<<<dim3(HID_ / 128, (B_ * N_) / 128), 256, 0, stream>>>(
      drug, Wd, bd, dp, B_ * N_, DD_, HID_);
  attn_pass1<<<HB_, 256, 0, stream>>>(t, dp, Wb, cnts, rm, rz, out);
  attn_pass2<<<HB_, 256, 0, stream>>>(t, dp, Wb, cnts, rm, rz, out);
}

// Round 2
// 804.295 us; speedup vs baseline: 1.4817x; 1.4817x over previous
//
#include <hip/hip_runtime.h>
#include <hip/hip_bf16.h>
#include <math.h>

#define B_ 32
#define N_ 128
#define L_ 1024
#define DD_ 256
#define TD_ 1280
#define HID_ 512
#define H_ 8
#define HD_ 64
#define LT 32
#define HB_ 256

// ws layout (float offsets)
#define WS_T 0
#define WS_D (WS_T + (size_t)B_*L_*HID_)          // 16777216
#define WS_RM (WS_D + (size_t)B_*N_*HID_)         // 18874368
#define WS_RZ (WS_RM + (size_t)H_*B_*N_)          // +32768
#define WS_CNT (WS_RZ + (size_t)H_*B_*N_)         // ints (64 floats reserved)
#define WS_WT (WS_CNT + 64)                        // bf16 WT[HID][TD] as ushort

using bf16x8 = __attribute__((ext_vector_type(8))) short;
using floatx4 = __attribute__((ext_vector_type(4))) float;

static __device__ __forceinline__ unsigned short f2bf(float f) {
  unsigned int u = __float_as_uint(f);
  unsigned int r = (u + 0x7FFFu + ((u >> 16) & 1u)) >> 16;
  return (unsigned short)r;
}

// ---------------------------------------------------------------------------
// K0: per-batch valid counts (detect int32 vs packed-bool at runtime).
// ---------------------------------------------------------------------------
__global__ __launch_bounds__(256) void count_kernel(const int* __restrict__ dmask,
                                                    const int* __restrict__ tmask,
                                                    int* __restrict__ cnts) {
  __shared__ int red[256];
  const int b = blockIdx.x, tid = threadIdx.x;
  const bool dint = (dmask[0] == 1);
  const bool tint = (tmask[0] == 1);
  int s = 0;
  if (dint) {
    for (int i = tid; i < N_; i += 256) s += (dmask[(size_t)b*N_ + i] != 0);
  } else {
    const unsigned char* p = (const unsigned char*)dmask;
    for (int i = tid; i < N_; i += 256) s += (p[(size_t)b*N_ + i] != 0);
  }
  red[tid] = s; __syncthreads();
  for (int off = 128; off > 0; off >>= 1) { if (tid < off) red[tid] += red[tid+off]; __syncthreads(); }
  if (tid == 0) cnts[b*2] = red[0];
  __syncthreads();
  s = 0;
  if (tint) {
    for (int i = tid; i < L_; i += 256) s += (tmask[(size_t)b*L_ + i] != 0);
  } else {
    const unsigned char* p = (const unsigned char*)tmask;
    for (int i = tid; i < L_; i += 256) s += (p[(size_t)b*L_ + i] != 0);
  }
  red[tid] = s; __syncthreads();
  for (int off = 128; off > 0; off >>= 1) { if (tid < off) red[tid] += red[tid+off]; __syncthreads(); }
  if (tid == 0) cnts[b*2+1] = red[0];
}

// ---------------------------------------------------------------------------
// K0b: W (KxN fp32) -> WT (NxK bf16), 32x32 LDS tiles.
// ---------------------------------------------------------------------------
__global__ __launch_bounds__(256) void transpose_bf16_kernel(
    const float* __restrict__ W, unsigned short* __restrict__ WT, int K, int Nd) {
  __shared__ float tile[32][33];
  const int tid = threadIdx.x;
  const int n0 = blockIdx.x * 32, k0 = blockIdx.y * 32;
  const int c = tid & 31, r0 = tid >> 5;
#pragma unroll
  for (int i = 0; i < 4; i++) {
    const int r = r0 + i * 8;
    tile[c][r] = W[(size_t)(k0 + r) * Nd + n0 + c];
  }
  __syncthreads();
#pragma unroll
  for (int i = 0; i < 4; i++) {
    const int r = r0 + i * 8;
    WT[(size_t)(n0 + r) * K + k0 + c] = f2bf(tile[r][c]);
  }
}

// ---------------------------------------------------------------------------
// K1-MFMA: C = A(MxK fp32) @ W(KxN) + bias via bf16 MFMA, fp32 accumulate.
// WT is pre-transposed bf16 [N][K]. 128x128 tile, BK=32, 256 threads (4 waves,
// each 64x64 as 4x4 grid of 16x16x32 MFMAs). A converted fp32->bf16 in
// staging. LDS rows padded to 40 elems (80 B, b128-aligned).
// ---------------------------------------------------------------------------
__global__ __launch_bounds__(256) void gemm_bias_mfma_kernel(
    const float* __restrict__ A, const unsigned short* __restrict__ WT,
    const float* __restrict__ bias, float* __restrict__ C,
    int M, int K, int Nd) {
  __shared__ __align__(16) unsigned short As[128 * 40];
  __shared__ __align__(16) unsigned short Bs[128 * 40];
  const int tid = threadIdx.x;
  const int m0 = blockIdx.y * 128, n0 = blockIdx.x * 128;
  const int srow = tid >> 1, shalf = tid & 1;       // staging: row, 16-elem half
  const int lane = tid & 63, wave = tid >> 6;
  const int wm = wave & 1, wn = wave >> 1;
  const int quad = lane >> 4, lrow = lane & 15;

  floatx4 acc[4][4];
#pragma unroll
  for (int i = 0; i < 4; i++)
#pragma unroll
    for (int j = 0; j < 4; j++) acc[i][j] = (floatx4){0.f, 0.f, 0.f, 0.f};

  const float* Aptr = A + (size_t)(m0 + srow) * K + shalf * 16;
  const unsigned short* Bptr = WT + (size_t)(n0 + srow) * K + shalf * 16;

  float4 a0 = *(const float4*)(Aptr + 0);
  float4 a1 = *(const float4*)(Aptr + 4);
  float4 a2 = *(const float4*)(Aptr + 8);
  float4 a3 = *(const float4*)(Aptr + 12);
  uint4 b0 = *(const uint4*)(Bptr + 0);
  uint4 b1 = *(const uint4*)(Bptr + 8);

  for (int k0 = 0; k0 < K; k0 += 32) {
    __syncthreads();
    {
      unsigned short* ap = &As[srow * 40 + shalf * 16];
      union { unsigned short s[8]; uint4 u; } pk;
      pk.s[0] = f2bf(a0.x); pk.s[1] = f2bf(a0.y); pk.s[2] = f2bf(a0.z); pk.s[3] = f2bf(a0.w);
      pk.s[4] = f2bf(a1.x); pk.s[5] = f2bf(a1.y); pk.s[6] = f2bf(a1.z); pk.s[7] = f2bf(a1.w);
      *(uint4*)ap = pk.u;
      pk.s[0] = f2bf(a2.x); pk.s[1] = f2bf(a2.y); pk.s[2] = f2bf(a2.z); pk.s[3] = f2bf(a2.w);
      pk.s[4] = f2bf(a3.x); pk.s[5] = f2bf(a3.y); pk.s[6] = f2bf(a3.z); pk.s[7] = f2bf(a3.w);
      *(uint4*)(ap + 8) = pk.u;
      unsigned short* bp = &Bs[srow * 40 + shalf * 16];
      *(uint4*)bp = b0;
      *(uint4*)(bp + 8) = b1;
    }
    __syncthreads();
    if (k0 + 32 < K) {
      a0 = *(const float4*)(Aptr + k0 + 32);
      a1 = *(const float4*)(Aptr + k0 + 36);
      a2 = *(const float4*)(Aptr + k0 + 40);
      a3 = *(const float4*)(Aptr + k0 + 44);
      b0 = *(const uint4*)(Bptr + k0 + 32);
      b1 = *(const uint4*)(Bptr + k0 + 40);
    }
    bf16x8 bfrag[4];
#pragma unroll
    for (int j = 0; j < 4; j++)
      bfrag[j] = *(const bf16x8*)&Bs[(wn * 64 + j * 16 + lrow) * 40 + quad * 8];
#pragma unroll
    for (int i = 0; i < 4; i++) {
      bf16x8 afrag = *(const bf16x8*)&As[(wm * 64 + i * 16 + lrow) * 40 + quad * 8];
#pragma unroll
      for (int j = 0; j < 4; j++)
        acc[i][j] = __builtin_amdgcn_mfma_f32_16x16x32_bf16(afrag, bfrag[j], acc[i][j], 0, 0, 0);
    }
  }

  float bj[4];
#pragma unroll
  for (int j = 0; j < 4; j++) bj[j] = bias[n0 + wn * 64 + j * 16 + lrow];
#pragma unroll
  for (int i = 0; i < 4; i++) {
    const int grow0 = m0 + wm * 64 + i * 16 + quad * 4;
#pragma unroll
    for (int j = 0; j < 4; j++) {
      const int gcol = n0 + wn * 64 + j * 16 + lrow;
#pragma unroll
      for (int r = 0; r < 4; r++)
        C[(size_t)(grow0 + r) * Nd + gcol] = acc[i][j][r] + bj[j];
    }
  }
}

// ---------------------------------------------------------------------------
// K1: fp32 GEMM (kept for the small d-projection; preserves score precision).
// ---------------------------------------------------------------------------
__global__ __launch_bounds__(256) void gemm_bias_kernel(
    const float* __restrict__ A, const float* __restrict__ W,
    const float* __restrict__ bias, float* __restrict__ C,
    int M, int K, int Nd) {
  __shared__ float As[8][132];
  __shared__ float Bs[8][132];
  const int tid = threadIdx.x;
  const int m0 = blockIdx.y * 128, n0 = blockIdx.x * 128;
  const int lr = tid >> 1, lc = (tid & 1) * 4;
  const int wr = tid >> 5, wc = (tid & 31) * 4;
  const int tm = (tid >> 4) * 4, tn = (tid & 15) * 4;

  float acc[2][2][4][4];
#pragma unroll
  for (int a = 0; a < 2; a++)
#pragma unroll
    for (int bq = 0; bq < 2; bq++)
#pragma unroll
      for (int i = 0; i < 4; i++)
#pragma unroll
        for (int j = 0; j < 4; j++) acc[a][bq][i][j] = 0.f;

  const float* Aptr = A + (size_t)(m0 + lr) * K + lc;
  const float* Wptr = W + (size_t)wr * Nd + n0 + wc;

  for (int k0 = 0; k0 < K; k0 += 8) {
    float4 a4 = *(const float4*)(Aptr + k0);
    float4 w4 = *(const float4*)(Wptr + (size_t)k0 * Nd);
    __syncthreads();
    As[lc+0][lr] = a4.x; As[lc+1][lr] = a4.y; As[lc+2][lr] = a4.z; As[lc+3][lr] = a4.w;
    *(float4*)&Bs[wr][wc] = w4;
    __syncthreads();
#pragma unroll
    for (int kk = 0; kk < 8; kk++) {
      float4 a0 = *(const float4*)&As[kk][tm];
      float4 a1 = *(const float4*)&As[kk][tm + 64];
      float4 b0 = *(const float4*)&Bs[kk][tn];
      float4 b1 = *(const float4*)&Bs[kk][tn + 64];
      const float av0[4] = {a0.x, a0.y, a0.z, a0.w};
      const float av1[4] = {a1.x, a1.y, a1.z, a1.w};
      const float bv0[4] = {b0.x, b0.y, b0.z, b0.w};
      const float bv1[4] = {b1.x, b1.y, b1.z, b1.w};
#pragma unroll
      for (int i = 0; i < 4; i++)
#pragma unroll
        for (int j = 0; j < 4; j++) {
          acc[0][0][i][j] += av0[i] * bv0[j];
          acc[0][1][i][j] += av0[i] * bv1[j];
          acc[1][0][i][j] += av1[i] * bv0[j];
          acc[1][1][i][j] += av1[i] * bv1[j];
        }
    }
  }
  float4 bias0 = *(const float4*)&bias[n0 + tn];
  float4 bias1 = *(const float4*)&bias[n0 + tn + 64];
  const float bb0[4] = {bias0.x, bias0.y, bias0.z, bias0.w};
  const float bb1[4] = {bias1.x, bias1.y, bias1.z, bias1.w};
#pragma unroll
  for (int mh = 0; mh < 2; mh++)
#pragma unroll
    for (int i = 0; i < 4; i++) {
      const int row = m0 + mh * 64 + tm + i;
      float* cp = C + (size_t)row * Nd + n0;
      float4 o0, o1;
      o0.x = acc[mh][0][i][0] + bb0[0]; o0.y = acc[mh][0][i][1] + bb0[1];
      o0.z = acc[mh][0][i][2] + bb0[2]; o0.w = acc[mh][0][i][3] + bb0[3];
      o1.x = acc[mh][1][i][0] + bb1[0]; o1.y = acc[mh][1][i][1] + bb1[1];
      o1.z = acc[mh][1][i][2] + bb1[2]; o1.w = acc[mh][1][i][3] + bb1[3];
      *(float4*)(cp + tn) = o0;
      *(float4*)(cp + tn + 64) = o1;
    }
}

// ---------------------------------------------------------------------------
// Attention helpers (unchanged from round 1).
// ---------------------------------------------------------------------------
__device__ __forceinline__ void compute_dW(const float* __restrict__ dproj,
                                           const float* __restrict__ Wb,
                                           float* __restrict__ dw_s,
                                           float* __restrict__ wbT,
                                           float* __restrict__ dbuf,
                                           int h, int b, int tid) {
  {
    const int r = tid >> 2;
    const int cc = tid & 3;
    const float* wb = Wb + (size_t)h * (HD_ * HD_) + (size_t)r * HD_;
#pragma unroll
    for (int c = 0; c < 4; c++) {
      const int e0 = (cc + 4 * c) * 4;
      float4 v = *(const float4*)(wb + e0);
      wbT[(e0+0)*68 + r] = v.x; wbT[(e0+1)*68 + r] = v.y;
      wbT[(e0+2)*68 + r] = v.z; wbT[(e0+3)*68 + r] = v.w;
    }
  }
  __syncthreads();
  const int r = tid >> 3, cc = tid & 7;
  const int e = tid & 63, ng = tid >> 6;
  for (int ch = 0; ch < 4; ch++) {
    const float* dp = dproj + ((size_t)(b * N_ + ch * 32 + r)) * HID_ + h * HD_;
    float4 v0 = *(const float4*)(dp + cc * 4);
    float4 v1 = *(const float4*)(dp + cc * 4 + 32);
    __syncthreads();
    *(float4*)&dbuf[r * 68 + cc * 4] = v0;
    *(float4*)&dbuf[r * 68 + cc * 4 + 32] = v1;
    __syncthreads();
    float accv[8];
#pragma unroll
    for (int i = 0; i < 8; i++) accv[i] = 0.f;
    for (int k4 = 0; k4 < 16; k4++) {
      float4 wv = *(const float4*)&wbT[e * 68 + k4 * 4];
#pragma unroll
      for (int i = 0; i < 8; i++) {
        float4 dv = *(const float4*)&dbuf[(ng + 4 * i) * 68 + k4 * 4];
        accv[i] += dv.x * wv.x + dv.y * wv.y + dv.z * wv.z + dv.w * wv.w;
      }
    }
#pragma unroll
    for (int i = 0; i < 8; i++) dw_s[(ch * 32 + ng + 4 * i) * 68 + e] = accv[i];
  }
  __syncthreads();
}

__device__ __forceinline__ void load_th_tile(const float* __restrict__ tproj,
                                             float* __restrict__ th_s,
                                             int b, int h, int l0, int tid) {
  const int r = tid >> 3, cc = tid & 7;
  const float* tp = tproj + ((size_t)(b * L_ + l0 + r)) * HID_ + h * HD_;
  float4 v0 = *(const float4*)(tp + cc * 4);
  float4 v1 = *(const float4*)(tp + cc * 4 + 32);
  __syncthreads();
  *(float4*)&th_s[r * 68 + cc * 4] = v0;
  *(float4*)&th_s[r * 68 + cc * 4 + 32] = v1;
}

__device__ __forceinline__ void compute_S(const float* __restrict__ dw_s,
                                          const float* __restrict__ th_s,
                                          float* __restrict__ S_s, int tid) {
  const int lg = tid & 7, ng = tid >> 3;
  float acc[4][4];
#pragma unroll
  for (int i = 0; i < 4; i++)
#pragma unroll
    for (int j = 0; j < 4; j++) acc[i][j] = 0.f;
  for (int k4 = 0; k4 < 16; k4++) {
    float4 tv[4], dv[4];
#pragma unroll
    for (int j = 0; j < 4; j++) tv[j] = *(const float4*)&th_s[(lg + 8 * j) * 68 + k4 * 4];
#pragma unroll
    for (int i = 0; i < 4; i++) dv[i] = *(const float4*)&dw_s[(ng + 32 * i) * 68 + k4 * 4];
#pragma unroll
    for (int i = 0; i < 4; i++)
#pragma unroll
      for (int j = 0; j < 4; j++)
        acc[i][j] += dv[i].x * tv[j].x + dv[i].y * tv[j].y + dv[i].z * tv[j].z + dv[i].w * tv[j].w;
  }
#pragma unroll
  for (int i = 0; i < 4; i++)
#pragma unroll
    for (int j = 0; j < 4; j++) S_s[(ng + 32 * i) * 33 + lg + 8 * j] = acc[i][j];
}

__global__ __launch_bounds__(256) void attn_pass1(
    const float* __restrict__ tproj, const float* __restrict__ dproj,
    const float* __restrict__ Wb, const int* __restrict__ cnts,
    float* __restrict__ rowm, float* __restrict__ rowz,
    float* __restrict__ outp) {
  __shared__ float dw_s[128 * 68];
  __shared__ float bufB[6528];
  __shared__ float cm_s[32], ics_s[32], colpart[256], wv_s[128];
  const int tid = threadIdx.x;
  const int hb = blockIdx.x;
  const int h = hb >> 5, b = hb & 31;

  compute_dW(dproj, Wb, dw_s, bufB, bufB + 64 * 68, h, b, tid);

  float* th_s = bufB;
  float* S_s = bufB + 32 * 68;
  const int ncnt = cnts[b * 2];
  const int lcnt = cnts[b * 2 + 1];
  const int ntiles = (lcnt + LT - 1) / LT;

  float m_r = -INFINITY, z_r = 0.f, w_r = 0.f;

  for (int tI = 0; tI < ntiles; tI++) {
    const int l0 = tI * LT;
    const int lv = min(LT, lcnt - l0);
    load_th_tile(tproj, th_s, b, h, l0, tid);
    __syncthreads();
    compute_S(dw_s, th_s, S_s, tid);
    __syncthreads();
    {
      const int l = tid & 31, q = tid >> 5;
      float pm = -INFINITY;
      if (l < lv) {
        const int nbeg = q * 16, nend = min(nbeg + 16, ncnt);
        for (int n = nbeg; n < nend; n++) pm = fmaxf(pm, S_s[n * 33 + l]);
      }
      colpart[q * 32 + l] = pm;
    }
    __syncthreads();
    if (tid < lv) {
      float cmax = colpart[tid];
#pragma unroll
      for (int q = 1; q < 8; q++) cmax = fmaxf(cmax, colpart[q * 32 + tid]);
      cm_s[tid] = cmax;
    }
    __syncthreads();
    {
      const int l = tid & 31, q = tid >> 5;
      float ps = 0.f;
      if (l < lv) {
        const float cmax = cm_s[l];
        const int nbeg = q * 16, nend = min(nbeg + 16, ncnt);
        for (int n = nbeg; n < nend; n++) ps += __expf(S_s[n * 33 + l] - cmax);
      }
      colpart[q * 32 + l] = ps;
    }
    __syncthreads();
    if (tid < lv) {
      float cs = 0.f;
#pragma unroll
      for (int q = 0; q < 8; q++) cs += colpart[q * 32 + tid];
      ics_s[tid] = 1.f / cs;
    }
    __syncthreads();
    if (tid < ncnt) {
      const int n = tid;
      float tmax = -INFINITY;
      for (int l = 0; l < lv; l++) tmax = fmaxf(tmax, S_s[n * 33 + l]);
      const float mnew = fmaxf(m_r, tmax);
      z_r *= __expf(m_r - mnew);
      for (int l = 0; l < lv; l++) {
        const float s = S_s[n * 33 + l];
        z_r += __expf(s - mnew);
        w_r += __expf(s - cm_s[l]) * ics_s[l];
      }
      m_r = mnew;
    }
    __syncthreads();
  }
  if (tid < 128) wv_s[tid] = (tid < ncnt) ? w_r : 0.f;
  if (tid < ncnt) {
    rowm[(size_t)hb * 128 + tid] = m_r;
    rowz[(size_t)hb * 128 + tid] = z_r;
  }
  __syncthreads();
  if (tid < 64) {
    float a = 0.f;
    const float* dp = dproj + (size_t)b * N_ * HID_ + h * HD_ + tid;
    for (int n = 0; n < ncnt; n++) a += wv_s[n] * dp[(size_t)n * HID_];
    outp[(size_t)b * (2 * HID_) + HID_ + h * HD_ + tid] = a / (float)lcnt;
  }
}

__global__ __launch_bounds__(256) void attn_pass2(
    const float* __restrict__ tproj, const float* __restrict__ dproj,
    const float* __restrict__ Wb, const int* __restrict__ cnts,
    const float* __restrict__ rowm, const float* __restrict__ rowz,
    float* __restrict__ outp) {
  __shared__ float dw_s[128 * 68];
  __shared__ float bufB[6528];
  __shared__ float rm_s[128], riz_s[128], vpart[256], v_s[32];
  const int tid = threadIdx.x;
  const int hb = blockIdx.x;
  const int h = hb >> 5, b = hb & 31;

  compute_dW(dproj, Wb, dw_s, bufB, bufB + 64 * 68, h, b, tid);

  float* th_s = bufB;
  float* S_s = bufB + 32 * 68;
  const int ncnt = cnts[b * 2];
  const int lcnt = cnts[b * 2 + 1];
  const int ntiles = (lcnt + LT - 1) / LT;

  if (tid < 128 && tid < ncnt) {
    rm_s[tid] = rowm[(size_t)hb * 128 + tid];
    riz_s[tid] = 1.f / rowz[(size_t)hb * 128 + tid];
  }
  __syncthreads();

  float ctx = 0.f;
  for (int tI = 0; tI < ntiles; tI++) {
    const int l0 = tI * LT;
    const int lv = min(LT, lcnt - l0);
    load_th_tile(tproj, th_s, b, h, l0, tid);
    __syncthreads();
    compute_S(dw_s, th_s, S_s, tid);
    __syncthreads();
    {
      const int l = tid & 31, q = tid >> 5;
      float vp = 0.f;
      if (l < lv) {
        const int nbeg = q * 16, nend = min(nbeg + 16, ncnt);
        for (int n = nbeg; n < nend; n++)
          vp += __expf(S_s[n * 33 + l] - rm_s[n]) * riz_s[n];
      }
      vpart[q * 32 + l] = vp;
    }
    __syncthreads();
    if (tid < lv) {
      float v = 0.f;
#pragma unroll
      for (int q = 0; q < 8; q++) v += vpart[q * 32 + tid];
      v_s[tid] = v;
    }
    __syncthreads();
    if (tid < 64) {
      for (int l = 0; l < lv; l++) ctx += v_s[l] * th_s[l * 68 + tid];
    }
    __syncthreads();
  }
  if (tid < 64) {
    outp[(size_t)b * (2 * HID_) + h * HD_ + tid] = ctx / (float)ncnt;
  }
}

// ---------------------------------------------------------------------------
extern "C" void kernel_launch(void* const* d_in, const int* in_sizes, int n_in,
                              void* d_out, int out_size, void* d_ws, size_t ws_size,
                              hipStream_t stream) {
  const float* drug = (const float*)d_in[0];
  const int* dmask = (const int*)d_in[1];
  const float* tseq = (const float*)d_in[2];
  const int* tmask = (const int*)d_in[3];
  const float* Wd = (const float*)d_in[4];
  const float* bd = (const float*)d_in[5];
  const float* Wt = (const float*)d_in[6];
  const float* bt = (const float*)d_in[7];
  const float* Wb = (const float*)d_in[8];
  float* out = (float*)d_out;
  float* ws = (float*)d_ws;

  float* t = ws + WS_T;
  float* dp = ws + WS_D;
  float* rm = ws + WS_RM;
  float* rz = ws + WS_RZ;
  int* cnts = (int*)(ws + WS_CNT);
  unsigned short* wtT = (unsigned short*)(ws + WS_WT);   // [HID_][TD_] bf16

  count_kernel<<<B_, 256, 0, stream>>>(dmask, tmask, cnts);
  transpose_bf16_kernel<<<dim3(HID_ / 32, TD_ / 32), 256, 0, stream>>>(Wt, wtT, TD_, HID_);
  gemm_bias_mfma_kernel<<<dim3(HID_ / 128, (B_ * L_) / 128), 256, 0, stream>>>(
      tseq, wtT, bt, t, B_ * L_, TD_, HID_);
  gemm_bias_kernel<<<dim3(HID_ / 128, (B_ * N_) / 128), 256, 0, stream>>>(
      drug, Wd, bd, dp, B_ * N_, DD_, HID_);
  attn_pass1<<<HB_, 256, 0, stream>>>(t, dp, Wb, cnts, rm, rz, out);
  attn_pass2<<<HB_, 256, 0, stream>>>(t, dp, Wb, cnts, rm, rz, out);
}

// Round 3
// 572.542 us; speedup vs baseline: 2.0815x; 1.4048x over previous
//
#include <hip/hip_runtime.h>
#include <hip/hip_bf16.h>
#include <math.h>

#define B_ 32
#define N_ 128
#define L_ 1024
#define DD_ 256
#define TD_ 1280
#define HID_ 512
#define H_ 8
#define HD_ 64

// ws layout (float offsets)
#define WS_D    0
#define WS_RM   (WS_D   + 2097152)
#define WS_RIZ  (WS_RM  + 32768)
#define WS_RMT  (WS_RIZ + 32768)
#define WS_RZT  (WS_RMT + 524288)
#define WS_W    (WS_RZT + 524288)
#define WS_V    (WS_W   + 32768)
#define WS_CNT  (WS_V   + 262144)
#define WS_WT   (WS_CNT + 64)
#define WS_THB  (WS_WT  + 327680)
#define WS_DWB  (WS_THB + 8388608)

using bf16x8 = __attribute__((ext_vector_type(8))) short;
using floatx4 = __attribute__((ext_vector_type(4))) float;

static __device__ __forceinline__ unsigned short f2bf(float f) {
  unsigned int u = __float_as_uint(f);
  unsigned int r = (u + 0x7FFFu + ((u >> 16) & 1u)) >> 16;
  return (unsigned short)r;
}
static __device__ __forceinline__ float bf2f(unsigned short s) {
  return __uint_as_float(((unsigned int)s) << 16);
}

// ---------------------------------------------------------------------------
// K0: per-batch valid counts (detect int32 vs packed-bool at runtime).
// ---------------------------------------------------------------------------
__global__ __launch_bounds__(256) void count_kernel(const int* __restrict__ dmask,
                                                    const int* __restrict__ tmask,
                                                    int* __restrict__ cnts) {
  __shared__ int red[256];
  const int b = blockIdx.x, tid = threadIdx.x;
  const bool dint = (dmask[0] == 1);
  const bool tint = (tmask[0] == 1);
  int s = 0;
  if (dint) {
    for (int i = tid; i < N_; i += 256) s += (dmask[(size_t)b*N_ + i] != 0);
  } else {
    const unsigned char* p = (const unsigned char*)dmask;
    for (int i = tid; i < N_; i += 256) s += (p[(size_t)b*N_ + i] != 0);
  }
  red[tid] = s; __syncthreads();
  for (int off = 128; off > 0; off >>= 1) { if (tid < off) red[tid] += red[tid+off]; __syncthreads(); }
  if (tid == 0) cnts[b*2] = red[0];
  __syncthreads();
  s = 0;
  if (tint) {
    for (int i = tid; i < L_; i += 256) s += (tmask[(size_t)b*L_ + i] != 0);
  } else {
    const unsigned char* p = (const unsigned char*)tmask;
    for (int i = tid; i < L_; i += 256) s += (p[(size_t)b*L_ + i] != 0);
  }
  red[tid] = s; __syncthreads();
  for (int off = 128; off > 0; off >>= 1) { if (tid < off) red[tid] += red[tid+off]; __syncthreads(); }
  if (tid == 0) cnts[b*2+1] = red[0];
}

// ---------------------------------------------------------------------------
// K0b: W (KxN fp32) -> WT (NxK bf16), 32x32 LDS tiles.
// ---------------------------------------------------------------------------
__global__ __launch_bounds__(256) void transpose_bf16_kernel(
    const float* __restrict__ W, unsigned short* __restrict__ WT, int K, int Nd) {
  __shared__ float tile[32][33];
  const int tid = threadIdx.x;
  const int n0 = blockIdx.x * 32, k0 = blockIdx.y * 32;
  const int c = tid & 31, r0 = tid >> 5;
#pragma unroll
  for (int i = 0; i < 4; i++) {
    const int r = r0 + i * 8;
    tile[c][r] = W[(size_t)(k0 + r) * Nd + n0 + c];
  }
  __syncthreads();
#pragma unroll
  for (int i = 0; i < 4; i++) {
    const int r = r0 + i * 8;
    WT[(size_t)(n0 + r) * K + k0 + c] = f2bf(tile[r][c]);
  }
}

// ---------------------------------------------------------------------------
// K1: t-projection via bf16 MFMA; writes head-major bf16 thb[b][h][l][64].
// ---------------------------------------------------------------------------
__global__ __launch_bounds__(256) void gemm_t_mfma_kernel(
    const float* __restrict__ A, const unsigned short* __restrict__ WT,
    const float* __restrict__ bias, unsigned short* __restrict__ thb,
    int M, int K) {
  __shared__ __align__(16) unsigned short As[128 * 40];
  __shared__ __align__(16) unsigned short Bs[128 * 40];
  const int tid = threadIdx.x;
  const int m0 = blockIdx.y * 128, n0 = blockIdx.x * 128;
  const int srow = tid >> 1, shalf = tid & 1;
  const int lane = tid & 63, wave = tid >> 6;
  const int wm = wave & 1, wn = wave >> 1;
  const int quad = lane >> 4, lrow = lane & 15;

  floatx4 acc[4][4];
#pragma unroll
  for (int i = 0; i < 4; i++)
#pragma unroll
    for (int j = 0; j < 4; j++) acc[i][j] = (floatx4){0.f, 0.f, 0.f, 0.f};

  const float* Aptr = A + (size_t)(m0 + srow) * K + shalf * 16;
  const unsigned short* Bptr = WT + (size_t)(n0 + srow) * K + shalf * 16;

  float4 a0 = *(const float4*)(Aptr + 0);
  float4 a1 = *(const float4*)(Aptr + 4);
  float4 a2 = *(const float4*)(Aptr + 8);
  float4 a3 = *(const float4*)(Aptr + 12);
  uint4 b0 = *(const uint4*)(Bptr + 0);
  uint4 b1 = *(const uint4*)(Bptr + 8);

  for (int k0 = 0; k0 < K; k0 += 32) {
    __syncthreads();
    {
      unsigned short* ap = &As[srow * 40 + shalf * 16];
      union { unsigned short s[8]; uint4 u; } pk;
      pk.s[0] = f2bf(a0.x); pk.s[1] = f2bf(a0.y); pk.s[2] = f2bf(a0.z); pk.s[3] = f2bf(a0.w);
      pk.s[4] = f2bf(a1.x); pk.s[5] = f2bf(a1.y); pk.s[6] = f2bf(a1.z); pk.s[7] = f2bf(a1.w);
      *(uint4*)ap = pk.u;
      pk.s[0] = f2bf(a2.x); pk.s[1] = f2bf(a2.y); pk.s[2] = f2bf(a2.z); pk.s[3] = f2bf(a2.w);
      pk.s[4] = f2bf(a3.x); pk.s[5] = f2bf(a3.y); pk.s[6] = f2bf(a3.z); pk.s[7] = f2bf(a3.w);
      *(uint4*)(ap + 8) = pk.u;
      unsigned short* bp = &Bs[srow * 40 + shalf * 16];
      *(uint4*)bp = b0;
      *(uint4*)(bp + 8) = b1;
    }
    __syncthreads();
    if (k0 + 32 < K) {
      a0 = *(const float4*)(Aptr + k0 + 32);
      a1 = *(const float4*)(Aptr + k0 + 36);
      a2 = *(const float4*)(Aptr + k0 + 40);
      a3 = *(const float4*)(Aptr + k0 + 44);
      b0 = *(const uint4*)(Bptr + k0 + 32);
      b1 = *(const uint4*)(Bptr + k0 + 40);
    }
    bf16x8 bfrag[4];
#pragma unroll
    for (int j = 0; j < 4; j++)
      bfrag[j] = *(const bf16x8*)&Bs[(wn * 64 + j * 16 + lrow) * 40 + quad * 8];
#pragma unroll
    for (int i = 0; i < 4; i++) {
      bf16x8 afrag = *(const bf16x8*)&As[(wm * 64 + i * 16 + lrow) * 40 + quad * 8];
#pragma unroll
      for (int j = 0; j < 4; j++)
        acc[i][j] = __builtin_amdgcn_mfma_f32_16x16x32_bf16(afrag, bfrag[j], acc[i][j], 0, 0, 0);
    }
  }

  float bj[4];
#pragma unroll
  for (int j = 0; j < 4; j++) bj[j] = bias[n0 + wn * 64 + j * 16 + lrow];
#pragma unroll
  for (int i = 0; i < 4; i++) {
#pragma unroll
    for (int j = 0; j < 4; j++) {
      const int gcol = n0 + wn * 64 + j * 16 + lrow;
      const int hh = gcol >> 6, e = gcol & 63;
#pragma unroll
      for (int r = 0; r < 4; r++) {
        const int grow = m0 + wm * 64 + i * 16 + quad * 4 + r;
        const int bb = grow >> 10, l = grow & 1023;
        thb[(((size_t)bb * H_ + hh) * L_ + l) * HD_ + e] = f2bf(acc[i][j][r] + bj[j]);
      }
    }
  }
}

// ---------------------------------------------------------------------------
// K2: fp32 GEMM for the small d-projection (keeps dproj exact for ctx_t).
// ---------------------------------------------------------------------------
__global__ __launch_bounds__(256) void gemm_bias_kernel(
    const float* __restrict__ A, const float* __restrict__ W,
    const float* __restrict__ bias, float* __restrict__ C,
    int M, int K, int Nd) {
  __shared__ float As[8][132];
  __shared__ float Bs[8][132];
  const int tid = threadIdx.x;
  const int m0 = blockIdx.y * 128, n0 = blockIdx.x * 128;
  const int lr = tid >> 1, lc = (tid & 1) * 4;
  const int wr = tid >> 5, wc = (tid & 31) * 4;
  const int tm = (tid >> 4) * 4, tn = (tid & 15) * 4;

  float acc[2][2][4][4];
#pragma unroll
  for (int a = 0; a < 2; a++)
#pragma unroll
    for (int bq = 0; bq < 2; bq++)
#pragma unroll
      for (int i = 0; i < 4; i++)
#pragma unroll
        for (int j = 0; j < 4; j++) acc[a][bq][i][j] = 0.f;

  const float* Aptr = A + (size_t)(m0 + lr) * K + lc;
  const float* Wptr = W + (size_t)wr * Nd + n0 + wc;

  for (int k0 = 0; k0 < K; k0 += 8) {
    float4 a4 = *(const float4*)(Aptr + k0);
    float4 w4 = *(const float4*)(Wptr + (size_t)k0 * Nd);
    __syncthreads();
    As[lc+0][lr] = a4.x; As[lc+1][lr] = a4.y; As[lc+2][lr] = a4.z; As[lc+3][lr] = a4.w;
    *(float4*)&Bs[wr][wc] = w4;
    __syncthreads();
#pragma unroll
    for (int kk = 0; kk < 8; kk++) {
      float4 a0 = *(const float4*)&As[kk][tm];
      float4 a1 = *(const float4*)&As[kk][tm + 64];
      float4 b0 = *(const float4*)&Bs[kk][tn];
      float4 b1 = *(const float4*)&Bs[kk][tn + 64];
      const float av0[4] = {a0.x, a0.y, a0.z, a0.w};
      const float av1[4] = {a1.x, a1.y, a1.z, a1.w};
      const float bv0[4] = {b0.x, b0.y, b0.z, b0.w};
      const float bv1[4] = {b1.x, b1.y, b1.z, b1.w};
#pragma unroll
      for (int i = 0; i < 4; i++)
#pragma unroll
        for (int j = 0; j < 4; j++) {
          acc[0][0][i][j] += av0[i] * bv0[j];
          acc[0][1][i][j] += av0[i] * bv1[j];
          acc[1][0][i][j] += av1[i] * bv0[j];
          acc[1][1][i][j] += av1[i] * bv1[j];
        }
    }
  }
  float4 bias0 = *(const float4*)&bias[n0 + tn];
  float4 bias1 = *(const float4*)&bias[n0 + tn + 64];
  const float bb0[4] = {bias0.x, bias0.y, bias0.z, bias0.w};
  const float bb1[4] = {bias1.x, bias1.y, bias1.z, bias1.w};
#pragma unroll
  for (int mh = 0; mh < 2; mh++)
#pragma unroll
    for (int i = 0; i < 4; i++) {
      const int row = m0 + mh * 64 + tm + i;
      float* cp = C + (size_t)row * Nd + n0;
      float4 o0, o1;
      o0.x = acc[mh][0][i][0] + bb0[0]; o0.y = acc[mh][0][i][1] + bb0[1];
      o0.z = acc[mh][0][i][2] + bb0[2]; o0.w = acc[mh][0][i][3] + bb0[3];
      o1.x = acc[mh][1][i][0] + bb1[0]; o1.y = acc[mh][1][i][1] + bb1[1];
      o1.z = acc[mh][1][i][2] + bb1[2]; o1.w = acc[mh][1][i][3] + bb1[3];
      *(float4*)(cp + tn) = o0;
      *(float4*)(cp + tn + 64) = o1;
    }
}

// ---------------------------------------------------------------------------
// K3: dWb[b][h][n][e] = (dh @ Wb[h]) in bf16. grid = 256 (hb = b*8+h).
// ---------------------------------------------------------------------------
__global__ __launch_bounds__(256) void dw_kernel(
    const float* __restrict__ dproj, const float* __restrict__ Wb,
    unsigned short* __restrict__ dWb) {
  __shared__ float wb_s[64 * 64];
  const int tid = threadIdx.x;
  const int hb = blockIdx.x, b = hb >> 3, h = hb & 7;
  for (int i = tid; i < 4096; i += 256) wb_s[i] = Wb[(size_t)h * 4096 + i];
  __syncthreads();
  const int n = tid >> 1, half = tid & 1;
  float acc[32];
#pragma unroll
  for (int e = 0; e < 32; e++) acc[e] = 0.f;
  const float* dpr = dproj + ((size_t)(b * N_ + n)) * HID_ + h * HD_;
  for (int k = 0; k < 64; k++) {
    const float a = dpr[k];
    const float* wr = &wb_s[k * 64 + half * 32];
#pragma unroll
    for (int e = 0; e < 32; e++) acc[e] += a * wr[e];
  }
  unsigned short* outp = dWb + ((size_t)hb * N_ + n) * HD_ + half * 32;
#pragma unroll
  for (int e = 0; e < 32; e++) outp[e] = f2bf(acc[e]);
}

// ---------------------------------------------------------------------------
// S-tile (128n x 64l) via MFMA, operands from global bf16 head-major arrays;
// masked fp32 S to LDS (stride 69: 2-way banks on row and column walks).
// ---------------------------------------------------------------------------
__device__ __forceinline__ void mfma_S_tile(
    const unsigned short* __restrict__ thp, const unsigned short* __restrict__ dwp,
    float* __restrict__ S_s, int ncnt, int lv, int tid) {
  const int lane = tid & 63, wave = tid >> 6;
  const int quad = lane >> 4, lr = lane & 15;
  const int noff = (wave & 1) * 64, loff = (wave >> 1) * 32;

  floatx4 acc[4][2];
#pragma unroll
  for (int i = 0; i < 4; i++)
#pragma unroll
    for (int j = 0; j < 2; j++) acc[i][j] = (floatx4){0.f, 0.f, 0.f, 0.f};

#pragma unroll
  for (int kc = 0; kc < 2; kc++) {
    bf16x8 bfr[2];
#pragma unroll
    for (int j = 0; j < 2; j++)
      bfr[j] = *(const bf16x8*)&thp[(size_t)(loff + j * 16 + lr) * HD_ + kc * 32 + quad * 8];
#pragma unroll
    for (int i = 0; i < 4; i++) {
      bf16x8 afr = *(const bf16x8*)&dwp[(size_t)(noff + i * 16 + lr) * HD_ + kc * 32 + quad * 8];
#pragma unroll
      for (int j = 0; j < 2; j++)
        acc[i][j] = __builtin_amdgcn_mfma_f32_16x16x32_bf16(afr, bfr[j], acc[i][j], 0, 0, 0);
    }
  }
#pragma unroll
  for (int i = 0; i < 4; i++)
#pragma unroll
    for (int j = 0; j < 2; j++)
#pragma unroll
      for (int r = 0; r < 4; r++) {
        const int n = noff + i * 16 + quad * 4 + r;
        const int li = loff + j * 16 + lr;
        const bool ok = (n < ncnt) && (li < lv);
        S_s[n * 69 + li] = ok ? acc[i][j][r] : -1e9f;
      }
}

// ---------------------------------------------------------------------------
// K4: per (hb, lt): S tile -> column softmax (complete) -> w atomics;
// per-tile row stats (m_t, z_t). grid = 256*16.
// ---------------------------------------------------------------------------
__global__ __launch_bounds__(256, 4) void attn_stats_kernel(
    const unsigned short* __restrict__ thb, const unsigned short* __restrict__ dWb,
    const int* __restrict__ cnts, float* __restrict__ w_g,
    float* __restrict__ rmt, float* __restrict__ rzt) {
  __shared__ float S_s[128 * 69];
  __shared__ float red[256];
  __shared__ float cm_s[64], ics_s[64];
  const int tid = threadIdx.x;
  const int hb = blockIdx.x >> 4, lt = blockIdx.x & 15;
  const int b = hb >> 3;
  const int ncnt = cnts[b * 2], lcnt = cnts[b * 2 + 1];
  const int l0g = lt * 64;
  if (l0g >= lcnt) return;
  const int lv = min(64, lcnt - l0g);

  mfma_S_tile(thb + ((size_t)hb * L_ + l0g) * HD_, dWb + (size_t)hb * N_ * HD_,
              S_s, ncnt, lv, tid);
  __syncthreads();

  {
    const int l = tid & 63, q = tid >> 6;
    float pm = -INFINITY;
    for (int n = q * 32; n < q * 32 + 32; n++) pm = fmaxf(pm, S_s[n * 69 + l]);
    red[tid] = pm;
  }
  __syncthreads();
  if (tid < 64)
    cm_s[tid] = fmaxf(fmaxf(red[tid], red[tid + 64]), fmaxf(red[tid + 128], red[tid + 192]));
  __syncthreads();
  {
    const int l = tid & 63, q = tid >> 6;
    const float cm = cm_s[l];
    float ps = 0.f;
    for (int n = q * 32; n < q * 32 + 32; n++) ps += __expf(S_s[n * 69 + l] - cm);
    red[tid] = ps;
  }
  __syncthreads();
  if (tid < 64)
    ics_s[tid] = 1.f / (red[tid] + red[tid + 64] + red[tid + 128] + red[tid + 192]);
  __syncthreads();
  if (tid < 128) {
    const int n = tid;
    const float* Sr = &S_s[n * 69];
    float tmax = -INFINITY;
    for (int l = 0; l < lv; l++) tmax = fmaxf(tmax, Sr[l]);
    float z = 0.f, w = 0.f;
    for (int l = 0; l < lv; l++) {
      const float s = Sr[l];
      z += __expf(s - tmax);
      w += __expf(s - cm_s[l]) * ics_s[l];
    }
    rmt[((size_t)hb * 16 + lt) * 128 + n] = tmax;
    rzt[((size_t)hb * 16 + lt) * 128 + n] = z;
    if (w != 0.f) atomicAdd(&w_g[hb * 128 + n], w);
  }
}

// ---------------------------------------------------------------------------
// K5: combine per-tile row stats -> (m, 1/Z); finalize ctx_t. grid = 256.
// ---------------------------------------------------------------------------
__global__ __launch_bounds__(256) void attn_combine_kernel(
    const float* __restrict__ rmt, const float* __restrict__ rzt,
    const float* __restrict__ w_g, const float* __restrict__ dproj,
    const int* __restrict__ cnts, float* __restrict__ rm_g,
    float* __restrict__ riz_g, float* __restrict__ outp) {
  __shared__ float red[256];
  const int tid = threadIdx.x;
  const int hb = blockIdx.x, b = hb >> 3, h = hb & 7;
  const int ncnt = cnts[b * 2], lcnt = cnts[b * 2 + 1];
  const int ntl = (lcnt + 63) >> 6;
  if (tid < 128) {
    const int n = tid;
    float m = -INFINITY;
    for (int t = 0; t < ntl; t++)
      m = fmaxf(m, rmt[((size_t)hb * 16 + t) * 128 + n]);
    float Z = 0.f;
    for (int t = 0; t < ntl; t++)
      Z += rzt[((size_t)hb * 16 + t) * 128 + n] * __expf(rmt[((size_t)hb * 16 + t) * 128 + n] - m);
    rm_g[hb * 128 + n] = m;
    riz_g[hb * 128 + n] = (n < ncnt) ? 1.f / Z : 0.f;
  }
  const int e = tid & 63, q = tid >> 6;
  float p = 0.f;
  const int nb = q * 32, ne = min(nb + 32, ncnt);
  for (int n = nb; n < ne; n++)
    p += w_g[hb * 128 + n] * dproj[((size_t)(b * N_ + n)) * HID_ + h * HD_ + e];
  red[tid] = p;
  __syncthreads();
  if (tid < 64) {
    const float s = red[tid] + red[tid + 64] + red[tid + 128] + red[tid + 192];
    outp[(size_t)b * (2 * HID_) + HID_ + h * HD_ + tid] = s / (float)lcnt;
  }
}

// ---------------------------------------------------------------------------
// K6: recompute S tile; v[l] = sum_n exp(S-m[n])/Z[n]. grid = 256*16.
// ---------------------------------------------------------------------------
__global__ __launch_bounds__(256, 4) void attn_v_kernel(
    const unsigned short* __restrict__ thb, const unsigned short* __restrict__ dWb,
    const int* __restrict__ cnts, const float* __restrict__ rm_g,
    const float* __restrict__ riz_g, float* __restrict__ v_g) {
  __shared__ float S_s[128 * 69];
  __shared__ float red[256];
  __shared__ float rm_s[128], riz_s[128];
  const int tid = threadIdx.x;
  const int hb = blockIdx.x >> 4, lt = blockIdx.x & 15;
  const int b = hb >> 3;
  const int ncnt = cnts[b * 2], lcnt = cnts[b * 2 + 1];
  const int l0g = lt * 64;
  if (l0g >= lcnt) return;
  const int lv = min(64, lcnt - l0g);

  if (tid < 128) {
    rm_s[tid] = rm_g[hb * 128 + tid];
    riz_s[tid] = riz_g[hb * 128 + tid];
  }
  mfma_S_tile(thb + ((size_t)hb * L_ + l0g) * HD_, dWb + (size_t)hb * N_ * HD_,
              S_s, ncnt, lv, tid);
  __syncthreads();

  const int l = tid & 63, q = tid >> 6;
  float vp = 0.f;
  for (int n = q * 32; n < q * 32 + 32; n++)
    vp += __expf(S_s[n * 69 + l] - rm_s[n]) * riz_s[n];
  red[tid] = vp;
  __syncthreads();
  if (tid < 64 && tid < lv) {
    const float v = red[tid] + red[tid + 64] + red[tid + 128] + red[tid + 192];
    v_g[(size_t)hb * L_ + l0g + tid] = v;
  }
}

// ---------------------------------------------------------------------------
// K7: ctx_d[e] = sum_l v[l] * th[l][e] / ncnt. grid = 256.
// ---------------------------------------------------------------------------
__global__ __launch_bounds__(256) void ctx_d_kernel(
    const unsigned short* __restrict__ thb, const float* __restrict__ v_g,
    const int* __restrict__ cnts, float* __restrict__ outp) {
  __shared__ float red[256];
  const int tid = threadIdx.x;
  const int hb = blockIdx.x, b = hb >> 3, h = hb & 7;
  const int ncnt = cnts[b * 2], lcnt = cnts[b * 2 + 1];
  const int e = tid & 63, q = tid >> 6;
  float p = 0.f;
  const int lb = q * 256, le = min(lb + 256, lcnt);
  const unsigned short* tp = thb + (size_t)hb * L_ * HD_;
  for (int l = lb; l < le; l++)
    p += v_g[(size_t)hb * L_ + l] * bf2f(tp[(size_t)l * HD_ + e]);
  red[tid] = p;
  __syncthreads();
  if (tid < 64) {
    const float s = red[tid] + red[tid + 64] + red[tid + 128] + red[tid + 192];
    outp[(size_t)b * (2 * HID_) + h * HD_ + tid] = s / (float)ncnt;
  }
}

// ---------------------------------------------------------------------------
extern "C" void kernel_launch(void* const* d_in, const int* in_sizes, int n_in,
                              void* d_out, int out_size, void* d_ws, size_t ws_size,
                              hipStream_t stream) {
  const float* drug = (const float*)d_in[0];
  const int* dmask = (const int*)d_in[1];
  const float* tseq = (const float*)d_in[2];
  const int* tmask = (const int*)d_in[3];
  const float* Wd = (const float*)d_in[4];
  const float* bd = (const float*)d_in[5];
  const float* Wt = (const float*)d_in[6];
  const float* bt = (const float*)d_in[7];
  const float* Wb = (const float*)d_in[8];
  float* out = (float*)d_out;
  float* ws = (float*)d_ws;

  float* dp = ws + WS_D;
  float* rm = ws + WS_RM;
  float* riz = ws + WS_RIZ;
  float* rmt = ws + WS_RMT;
  float* rzt = ws + WS_RZT;
  float* w_g = ws + WS_W;
  float* v_g = ws + WS_V;
  int* cnts = (int*)(ws + WS_CNT);
  unsigned short* wtT = (unsigned short*)(ws + WS_WT);
  unsigned short* thb = (unsigned short*)(ws + WS_THB);
  unsigned short* dWb = (unsigned short*)(ws + WS_DWB);

  count_kernel<<<B_, 256, 0, stream>>>(dmask, tmask, cnts);
  hipMemsetAsync(w_g, 0, (size_t)(B_ * H_ * N_) * sizeof(float), stream);
  transpose_bf16_kernel<<<dim3(HID_ / 32, TD_ / 32), 256, 0, stream>>>(Wt, wtT, TD_, HID_);
  gemm_t_mfma_kernel<<<dim3(HID_ / 128, (B_ * L_) / 128), 256, 0, stream>>>(
      tseq, wtT, bt, thb, B_ * L_, TD_);
  gemm_bias_kernel<<<dim3(HID_ / 128, (B_ * N_) / 128), 256, 0, stream>>>(
      drug, Wd, bd, dp, B_ * N_, DD_, HID_);
  dw_kernel<<<B_ * H_, 256, 0, stream>>>(dp, Wb, dWb);
  attn_stats_kernel<<<B_ * H_ * 16, 256, 0, stream>>>(thb, dWb, cnts, w_g, rmt, rzt);
  attn_combine_kernel<<<B_ * H_, 256, 0, stream>>>(rmt, rzt, w_g, dp, cnts, rm, riz, out);
  attn_v_kernel<<<B_ * H_ * 16, 256, 0, stream>>>(thb, dWb, cnts, rm, riz, v_g);
  ctx_d_kernel<<<B_ * H_, 256, 0, stream>>>(thb, v_g, cnts, out);
}

// Round 4
// 486.534 us; speedup vs baseline: 2.4495x; 1.1768x over previous
//
#include <hip/hip_runtime.h>
#include <hip/hip_bf16.h>
#include <math.h>

#define B_ 32
#define N_ 128
#define L_ 1024
#define DD_ 256
#define TD_ 1280
#define HID_ 512
#define H_ 8
#define HD_ 64

// ws layout (float offsets)
#define WS_D    0
#define WS_RM   (WS_D   + 2097152)
#define WS_RIZ  (WS_RM  + 32768)
#define WS_RMT  (WS_RIZ + 32768)
#define WS_RZT  (WS_RMT + 524288)
#define WS_W    (WS_RZT + 524288)
#define WS_CNT  (WS_W   + 32768)
#define WS_WT   (WS_CNT + 64)
#define WS_THB  (WS_WT  + 327680)
#define WS_DWB  (WS_THB + 8388608)

using bf16x8 = __attribute__((ext_vector_type(8))) short;
using floatx4 = __attribute__((ext_vector_type(4))) float;

static __device__ __forceinline__ unsigned short f2bf(float f) {
  unsigned int u = __float_as_uint(f);
  unsigned int r = (u + 0x7FFFu + ((u >> 16) & 1u)) >> 16;
  return (unsigned short)r;
}
static __device__ __forceinline__ float bf2f(unsigned short s) {
  return __uint_as_float(((unsigned int)s) << 16);
}

// ---------------------------------------------------------------------------
// K0: per-batch valid counts (detect int32 vs packed-bool at runtime).
// ---------------------------------------------------------------------------
__global__ __launch_bounds__(256) void count_kernel(const int* __restrict__ dmask,
                                                    const int* __restrict__ tmask,
                                                    int* __restrict__ cnts) {
  __shared__ int red[256];
  const int b = blockIdx.x, tid = threadIdx.x;
  const bool dint = (dmask[0] == 1);
  const bool tint = (tmask[0] == 1);
  int s = 0;
  if (dint) {
    for (int i = tid; i < N_; i += 256) s += (dmask[(size_t)b*N_ + i] != 0);
  } else {
    const unsigned char* p = (const unsigned char*)dmask;
    for (int i = tid; i < N_; i += 256) s += (p[(size_t)b*N_ + i] != 0);
  }
  red[tid] = s; __syncthreads();
  for (int off = 128; off > 0; off >>= 1) { if (tid < off) red[tid] += red[tid+off]; __syncthreads(); }
  if (tid == 0) cnts[b*2] = red[0];
  __syncthreads();
  s = 0;
  if (tint) {
    for (int i = tid; i < L_; i += 256) s += (tmask[(size_t)b*L_ + i] != 0);
  } else {
    const unsigned char* p = (const unsigned char*)tmask;
    for (int i = tid; i < L_; i += 256) s += (p[(size_t)b*L_ + i] != 0);
  }
  red[tid] = s; __syncthreads();
  for (int off = 128; off > 0; off >>= 1) { if (tid < off) red[tid] += red[tid+off]; __syncthreads(); }
  if (tid == 0) cnts[b*2+1] = red[0];
}

// ---------------------------------------------------------------------------
// K0b: W (KxN fp32) -> WT (NxK bf16), 32x32 LDS tiles.
// ---------------------------------------------------------------------------
__global__ __launch_bounds__(256) void transpose_bf16_kernel(
    const float* __restrict__ W, unsigned short* __restrict__ WT, int K, int Nd) {
  __shared__ float tile[32][33];
  const int tid = threadIdx.x;
  const int n0 = blockIdx.x * 32, k0 = blockIdx.y * 32;
  const int c = tid & 31, r0 = tid >> 5;
#pragma unroll
  for (int i = 0; i < 4; i++) {
    const int r = r0 + i * 8;
    tile[c][r] = W[(size_t)(k0 + r) * Nd + n0 + c];
  }
  __syncthreads();
#pragma unroll
  for (int i = 0; i < 4; i++) {
    const int r = r0 + i * 8;
    WT[(size_t)(n0 + r) * K + k0 + c] = f2bf(tile[r][c]);
  }
}

// ---------------------------------------------------------------------------
// K1: t-projection via bf16 MFMA; head-major bf16 output thb[b][h][l][64].
// XCD-swizzled 1D grid (1024 blocks): xcd = lin&7 processes its 32 m-tiles
// sequentially, the 4 n-tiles of one m-tile back-to-back -> A-tile fetched
// once per XCD L2 instead of 4x across XCDs.
// ---------------------------------------------------------------------------
__global__ __launch_bounds__(256) void gemm_t_mfma_kernel(
    const float* __restrict__ A, const unsigned short* __restrict__ WT,
    const float* __restrict__ bias, unsigned short* __restrict__ thb,
    int M, int K) {
  __shared__ __align__(16) unsigned short As[128 * 40];
  __shared__ __align__(16) unsigned short Bs[128 * 40];
  const int tid = threadIdx.x;
  const int lin = blockIdx.x;
  const int xcd = lin & 7, sq = lin >> 3;
  const int n_t = sq & 3, m_t = (sq >> 2) + xcd * 32;
  const int m0 = m_t * 128, n0 = n_t * 128;
  const int srow = tid >> 1, shalf = tid & 1;
  const int lane = tid & 63, wave = tid >> 6;
  const int wm = wave & 1, wn = wave >> 1;
  const int quad = lane >> 4, lrow = lane & 15;

  floatx4 acc[4][4];
#pragma unroll
  for (int i = 0; i < 4; i++)
#pragma unroll
    for (int j = 0; j < 4; j++) acc[i][j] = (floatx4){0.f, 0.f, 0.f, 0.f};

  const float* Aptr = A + (size_t)(m0 + srow) * K + shalf * 16;
  const unsigned short* Bptr = WT + (size_t)(n0 + srow) * K + shalf * 16;

  float4 a0 = *(const float4*)(Aptr + 0);
  float4 a1 = *(const float4*)(Aptr + 4);
  float4 a2 = *(const float4*)(Aptr + 8);
  float4 a3 = *(const float4*)(Aptr + 12);
  uint4 b0 = *(const uint4*)(Bptr + 0);
  uint4 b1 = *(const uint4*)(Bptr + 8);

  for (int k0 = 0; k0 < K; k0 += 32) {
    __syncthreads();
    {
      unsigned short* ap = &As[srow * 40 + shalf * 16];
      union { unsigned short s[8]; uint4 u; } pk;
      pk.s[0] = f2bf(a0.x); pk.s[1] = f2bf(a0.y); pk.s[2] = f2bf(a0.z); pk.s[3] = f2bf(a0.w);
      pk.s[4] = f2bf(a1.x); pk.s[5] = f2bf(a1.y); pk.s[6] = f2bf(a1.z); pk.s[7] = f2bf(a1.w);
      *(uint4*)ap = pk.u;
      pk.s[0] = f2bf(a2.x); pk.s[1] = f2bf(a2.y); pk.s[2] = f2bf(a2.z); pk.s[3] = f2bf(a2.w);
      pk.s[4] = f2bf(a3.x); pk.s[5] = f2bf(a3.y); pk.s[6] = f2bf(a3.z); pk.s[7] = f2bf(a3.w);
      *(uint4*)(ap + 8) = pk.u;
      unsigned short* bp = &Bs[srow * 40 + shalf * 16];
      *(uint4*)bp = b0;
      *(uint4*)(bp + 8) = b1;
    }
    __syncthreads();
    if (k0 + 32 < K) {
      a0 = *(const float4*)(Aptr + k0 + 32);
      a1 = *(const float4*)(Aptr + k0 + 36);
      a2 = *(const float4*)(Aptr + k0 + 40);
      a3 = *(const float4*)(Aptr + k0 + 44);
      b0 = *(const uint4*)(Bptr + k0 + 32);
      b1 = *(const uint4*)(Bptr + k0 + 40);
    }
    bf16x8 bfrag[4];
#pragma unroll
    for (int j = 0; j < 4; j++)
      bfrag[j] = *(const bf16x8*)&Bs[(wn * 64 + j * 16 + lrow) * 40 + quad * 8];
#pragma unroll
    for (int i = 0; i < 4; i++) {
      bf16x8 afrag = *(const bf16x8*)&As[(wm * 64 + i * 16 + lrow) * 40 + quad * 8];
#pragma unroll
      for (int j = 0; j < 4; j++)
        acc[i][j] = __builtin_amdgcn_mfma_f32_16x16x32_bf16(afrag, bfrag[j], acc[i][j], 0, 0, 0);
    }
  }

  float bj[4];
#pragma unroll
  for (int j = 0; j < 4; j++) bj[j] = bias[n0 + wn * 64 + j * 16 + lrow];
#pragma unroll
  for (int i = 0; i < 4; i++) {
#pragma unroll
    for (int j = 0; j < 4; j++) {
      const int gcol = n0 + wn * 64 + j * 16 + lrow;
      const int hh = gcol >> 6, e = gcol & 63;
#pragma unroll
      for (int r = 0; r < 4; r++) {
        const int grow = m0 + wm * 64 + i * 16 + quad * 4 + r;
        const int bb = grow >> 10, l = grow & 1023;
        thb[(((size_t)bb * H_ + hh) * L_ + l) * HD_ + e] = f2bf(acc[i][j][r] + bj[j]);
      }
    }
  }
}

// ---------------------------------------------------------------------------
// K2: fp32 GEMM for the small d-projection (keeps dproj exact for ctx_t).
// ---------------------------------------------------------------------------
__global__ __launch_bounds__(256) void gemm_bias_kernel(
    const float* __restrict__ A, const float* __restrict__ W,
    const float* __restrict__ bias, float* __restrict__ C,
    int M, int K, int Nd) {
  __shared__ float As[8][132];
  __shared__ float Bs[8][132];
  const int tid = threadIdx.x;
  const int m0 = blockIdx.y * 128, n0 = blockIdx.x * 128;
  const int lr = tid >> 1, lc = (tid & 1) * 4;
  const int wr = tid >> 5, wc = (tid & 31) * 4;
  const int tm = (tid >> 4) * 4, tn = (tid & 15) * 4;

  float acc[2][2][4][4];
#pragma unroll
  for (int a = 0; a < 2; a++)
#pragma unroll
    for (int bq = 0; bq < 2; bq++)
#pragma unroll
      for (int i = 0; i < 4; i++)
#pragma unroll
        for (int j = 0; j < 4; j++) acc[a][bq][i][j] = 0.f;

  const float* Aptr = A + (size_t)(m0 + lr) * K + lc;
  const float* Wptr = W + (size_t)wr * Nd + n0 + wc;

  for (int k0 = 0; k0 < K; k0 += 8) {
    float4 a4 = *(const float4*)(Aptr + k0);
    float4 w4 = *(const float4*)(Wptr + (size_t)k0 * Nd);
    __syncthreads();
    As[lc+0][lr] = a4.x; As[lc+1][lr] = a4.y; As[lc+2][lr] = a4.z; As[lc+3][lr] = a4.w;
    *(float4*)&Bs[wr][wc] = w4;
    __syncthreads();
#pragma unroll
    for (int kk = 0; kk < 8; kk++) {
      float4 a0 = *(const float4*)&As[kk][tm];
      float4 a1 = *(const float4*)&As[kk][tm + 64];
      float4 b0 = *(const float4*)&Bs[kk][tn];
      float4 b1 = *(const float4*)&Bs[kk][tn + 64];
      const float av0[4] = {a0.x, a0.y, a0.z, a0.w};
      const float av1[4] = {a1.x, a1.y, a1.z, a1.w};
      const float bv0[4] = {b0.x, b0.y, b0.z, b0.w};
      const float bv1[4] = {b1.x, b1.y, b1.z, b1.w};
#pragma unroll
      for (int i = 0; i < 4; i++)
#pragma unroll
        for (int j = 0; j < 4; j++) {
          acc[0][0][i][j] += av0[i] * bv0[j];
          acc[0][1][i][j] += av0[i] * bv1[j];
          acc[1][0][i][j] += av1[i] * bv0[j];
          acc[1][1][i][j] += av1[i] * bv1[j];
        }
    }
  }
  float4 bias0 = *(const float4*)&bias[n0 + tn];
  float4 bias1 = *(const float4*)&bias[n0 + tn + 64];
  const float bb0[4] = {bias0.x, bias0.y, bias0.z, bias0.w};
  const float bb1[4] = {bias1.x, bias1.y, bias1.z, bias1.w};
#pragma unroll
  for (int mh = 0; mh < 2; mh++)
#pragma unroll
    for (int i = 0; i < 4; i++) {
      const int row = m0 + mh * 64 + tm + i;
      float* cp = C + (size_t)row * Nd + n0;
      float4 o0, o1;
      o0.x = acc[mh][0][i][0] + bb0[0]; o0.y = acc[mh][0][i][1] + bb0[1];
      o0.z = acc[mh][0][i][2] + bb0[2]; o0.w = acc[mh][0][i][3] + bb0[3];
      o1.x = acc[mh][1][i][0] + bb1[0]; o1.y = acc[mh][1][i][1] + bb1[1];
      o1.z = acc[mh][1][i][2] + bb1[2]; o1.w = acc[mh][1][i][3] + bb1[3];
      *(float4*)(cp + tn) = o0;
      *(float4*)(cp + tn + 64) = o1;
    }
}

// ---------------------------------------------------------------------------
// K3: dWb[b][h][n][e] = (dh @ Wb[h]) in bf16. grid = 256 (hb = b*8+h).
// ---------------------------------------------------------------------------
__global__ __launch_bounds__(256) void dw_kernel(
    const float* __restrict__ dproj, const float* __restrict__ Wb,
    unsigned short* __restrict__ dWb) {
  __shared__ float wb_s[64 * 64];
  const int tid = threadIdx.x;
  const int hb = blockIdx.x, b = hb >> 3, h = hb & 7;
  for (int i = tid; i < 4096; i += 256) wb_s[i] = Wb[(size_t)h * 4096 + i];
  __syncthreads();
  const int n = tid >> 1, half = tid & 1;
  float acc[32];
#pragma unroll
  for (int e = 0; e < 32; e++) acc[e] = 0.f;
  const float* dpr = dproj + ((size_t)(b * N_ + n)) * HID_ + h * HD_;
  for (int k = 0; k < 64; k++) {
    const float a = dpr[k];
    const float* wr = &wb_s[k * 64 + half * 32];
#pragma unroll
    for (int e = 0; e < 32; e++) acc[e] += a * wr[e];
  }
  unsigned short* outp = dWb + ((size_t)hb * N_ + n) * HD_ + half * 32;
#pragma unroll
  for (int e = 0; e < 32; e++) outp[e] = f2bf(acc[e]);
}

// ---------------------------------------------------------------------------
// S-tile (128n x 64l) via MFMA, operands from global bf16 head-major arrays;
// masked fp32 S to LDS (stride 69: conflict-light on row and column walks).
// ---------------------------------------------------------------------------
__device__ __forceinline__ void mfma_S_tile(
    const unsigned short* __restrict__ thp, const unsigned short* __restrict__ dwp,
    float* __restrict__ S_s, int ncnt, int lv, int tid) {
  const int lane = tid & 63, wave = tid >> 6;
  const int quad = lane >> 4, lr = lane & 15;
  const int noff = (wave & 1) * 64, loff = (wave >> 1) * 32;

  floatx4 acc[4][2];
#pragma unroll
  for (int i = 0; i < 4; i++)
#pragma unroll
    for (int j = 0; j < 2; j++) acc[i][j] = (floatx4){0.f, 0.f, 0.f, 0.f};

#pragma unroll
  for (int kc = 0; kc < 2; kc++) {
    bf16x8 bfr[2];
#pragma unroll
    for (int j = 0; j < 2; j++)
      bfr[j] = *(const bf16x8*)&thp[(size_t)(loff + j * 16 + lr) * HD_ + kc * 32 + quad * 8];
#pragma unroll
    for (int i = 0; i < 4; i++) {
      bf16x8 afr = *(const bf16x8*)&dwp[(size_t)(noff + i * 16 + lr) * HD_ + kc * 32 + quad * 8];
#pragma unroll
      for (int j = 0; j < 2; j++)
        acc[i][j] = __builtin_amdgcn_mfma_f32_16x16x32_bf16(afr, bfr[j], acc[i][j], 0, 0, 0);
    }
  }
#pragma unroll
  for (int i = 0; i < 4; i++)
#pragma unroll
    for (int j = 0; j < 2; j++)
#pragma unroll
      for (int r = 0; r < 4; r++) {
        const int n = noff + i * 16 + quad * 4 + r;
        const int li = loff + j * 16 + lr;
        const bool ok = (n < ncnt) && (li < lv);
        S_s[n * 69 + li] = ok ? acc[i][j][r] : -1e9f;
      }
}

// ---------------------------------------------------------------------------
// K4: per (hb, lt): S tile -> column softmax (complete per tile) -> w atomics;
// per-tile row stats (m_t, z_t) with the row loop split across thread halves.
// grid = 256*16.
// ---------------------------------------------------------------------------
__global__ __launch_bounds__(256, 4) void attn_stats_kernel(
    const unsigned short* __restrict__ thb, const unsigned short* __restrict__ dWb,
    const int* __restrict__ cnts, float* __restrict__ w_g,
    float* __restrict__ rmt, float* __restrict__ rzt) {
  __shared__ float S_s[128 * 69];
  __shared__ float red[256];
  __shared__ float zb_s[256], wb_s[256];
  __shared__ float cm_s[64], ics_s[64];
  const int tid = threadIdx.x;
  const int hb = blockIdx.x >> 4, lt = blockIdx.x & 15;
  const int b = hb >> 3;
  const int ncnt = cnts[b * 2], lcnt = cnts[b * 2 + 1];
  const int l0g = lt * 64;
  if (l0g >= lcnt) return;
  const int lv = min(64, lcnt - l0g);

  mfma_S_tile(thb + ((size_t)hb * L_ + l0g) * HD_, dWb + (size_t)hb * N_ * HD_,
              S_s, ncnt, lv, tid);
  __syncthreads();

  {  // column max partials (over n)
    const int l = tid & 63, q = tid >> 6;
    float pm = -INFINITY;
    for (int n = q * 32; n < q * 32 + 32; n++) pm = fmaxf(pm, S_s[n * 69 + l]);
    red[tid] = pm;
  }
  __syncthreads();
  if (tid < 64)
    cm_s[tid] = fmaxf(fmaxf(red[tid], red[tid + 64]), fmaxf(red[tid + 128], red[tid + 192]));
  __syncthreads();
  {  // column expsum partials
    const int l = tid & 63, q = tid >> 6;
    const float cm = cm_s[l];
    float ps = 0.f;
    for (int n = q * 32; n < q * 32 + 32; n++) ps += __expf(S_s[n * 69 + l] - cm);
    red[tid] = ps;
  }
  __syncthreads();
  if (tid < 64)
    ics_s[tid] = 1.f / (red[tid] + red[tid + 64] + red[tid + 128] + red[tid + 192]);
  __syncthreads();
  {  // row pass, split across halves: n = tid&127, half covers 32 l's
    const int n = tid & 127, half = tid >> 7;
    const float* Sr = &S_s[n * 69];
    const int lb = half * 32, le = min(lb + 32, lv);
    float tmax = -INFINITY;
    for (int l = lb; l < le; l++) tmax = fmaxf(tmax, Sr[l]);
    red[tid] = tmax;
    __syncthreads();
    const float tm = fmaxf(red[n], red[n + 128]);
    float z = 0.f, w = 0.f;
    for (int l = lb; l < le; l++) {
      const float s = Sr[l];
      z += __expf(s - tm);
      w += __expf(s - cm_s[l]) * ics_s[l];
    }
    zb_s[tid] = z; wb_s[tid] = w;
    __syncthreads();
    if (tid < 128) {
      rmt[((size_t)hb * 16 + lt) * 128 + tid] = tm;
      rzt[((size_t)hb * 16 + lt) * 128 + tid] = zb_s[tid] + zb_s[tid + 128];
      const float wsum = wb_s[tid] + wb_s[tid + 128];
      if (wsum != 0.f) atomicAdd(&w_g[hb * 128 + tid], wsum);
    }
  }
}

// ---------------------------------------------------------------------------
// K5: combine per-tile row stats -> (m, 1/Z); finalize ctx_t. grid = 256.
// ---------------------------------------------------------------------------
__global__ __launch_bounds__(256) void attn_combine_kernel(
    const float* __restrict__ rmt, const float* __restrict__ rzt,
    const float* __restrict__ w_g, const float* __restrict__ dproj,
    const int* __restrict__ cnts, float* __restrict__ rm_g,
    float* __restrict__ riz_g, float* __restrict__ outp) {
  __shared__ float red[256];
  const int tid = threadIdx.x;
  const int hb = blockIdx.x, b = hb >> 3, h = hb & 7;
  const int ncnt = cnts[b * 2], lcnt = cnts[b * 2 + 1];
  const int ntl = (lcnt + 63) >> 6;
  if (tid < 128) {
    const int n = tid;
    float m = -INFINITY;
    for (int t = 0; t < ntl; t++)
      m = fmaxf(m, rmt[((size_t)hb * 16 + t) * 128 + n]);
    float Z = 0.f;
    for (int t = 0; t < ntl; t++)
      Z += rzt[((size_t)hb * 16 + t) * 128 + n] * __expf(rmt[((size_t)hb * 16 + t) * 128 + n] - m);
    rm_g[hb * 128 + n] = m;
    riz_g[hb * 128 + n] = (n < ncnt) ? 1.f / Z : 0.f;
  }
  const int e = tid & 63, q = tid >> 6;
  float p = 0.f;
  const int nb = q * 32, ne = min(nb + 32, ncnt);
  for (int n = nb; n < ne; n++)
    p += w_g[hb * 128 + n] * dproj[((size_t)(b * N_ + n)) * HID_ + h * HD_ + e];
  red[tid] = p;
  __syncthreads();
  if (tid < 64) {
    const float s = red[tid] + red[tid + 64] + red[tid + 128] + red[tid + 192];
    outp[(size_t)b * (2 * HID_) + HID_ + h * HD_ + tid] = s / (float)lcnt;
  }
}

// ---------------------------------------------------------------------------
// K6: recompute S tile; v[l] = sum_n exp(S-m[n])/Z[n]; fused ctx_d partial
// accumulation (atomicAdd into zero-initialized out). grid = 256*16.
// ---------------------------------------------------------------------------
__global__ __launch_bounds__(256, 4) void attn_v_kernel(
    const unsigned short* __restrict__ thb, const unsigned short* __restrict__ dWb,
    const int* __restrict__ cnts, const float* __restrict__ rm_g,
    const float* __restrict__ riz_g, float* __restrict__ outp) {
  __shared__ float S_s[128 * 69];
  __shared__ float red[256];
  __shared__ float rm_s[128], riz_s[128], v_s[64];
  const int tid = threadIdx.x;
  const int hb = blockIdx.x >> 4, lt = blockIdx.x & 15;
  const int b = hb >> 3, h = hb & 7;
  const int ncnt = cnts[b * 2], lcnt = cnts[b * 2 + 1];
  const int l0g = lt * 64;
  if (l0g >= lcnt) return;
  const int lv = min(64, lcnt - l0g);

  if (tid < 128) {
    rm_s[tid] = rm_g[hb * 128 + tid];
    riz_s[tid] = riz_g[hb * 128 + tid];
  }
  const unsigned short* thp = thb + ((size_t)hb * L_ + l0g) * HD_;
  mfma_S_tile(thp, dWb + (size_t)hb * N_ * HD_, S_s, ncnt, lv, tid);
  __syncthreads();

  {
    const int l = tid & 63, q = tid >> 6;
    float vp = 0.f;
    for (int n = q * 32; n < q * 32 + 32; n++)
      vp += __expf(S_s[n * 69 + l] - rm_s[n]) * riz_s[n];
    red[tid] = vp;
  }
  __syncthreads();
  const float incnt = 1.f / (float)ncnt;
  if (tid < 64) {
    const float v = (tid < lv)
        ? (red[tid] + red[tid + 64] + red[tid + 128] + red[tid + 192]) * incnt
        : 0.f;
    v_s[tid] = v;
  }
  __syncthreads();
  {  // fused ctx_d partial: sum_{l in tile} v[l] * th[l][e]
    const int e = tid & 63, q = tid >> 6;
    float p = 0.f;
    for (int l = q * 16; l < q * 16 + 16; l++)
      p += v_s[l] * bf2f(thp[(size_t)l * HD_ + e]);
    red[tid] = p;
  }
  __syncthreads();
  if (tid < 64) {
    const float s = red[tid] + red[tid + 64] + red[tid + 128] + red[tid + 192];
    if (s != 0.f)
      atomicAdd(&outp[(size_t)b * (2 * HID_) + h * HD_ + tid], s);
  }
}

// ---------------------------------------------------------------------------
extern "C" void kernel_launch(void* const* d_in, const int* in_sizes, int n_in,
                              void* d_out, int out_size, void* d_ws, size_t ws_size,
                              hipStream_t stream) {
  const float* drug = (const float*)d_in[0];
  const int* dmask = (const int*)d_in[1];
  const float* tseq = (const float*)d_in[2];
  const int* tmask = (const int*)d_in[3];
  const float* Wd = (const float*)d_in[4];
  const float* bd = (const float*)d_in[5];
  const float* Wt = (const float*)d_in[6];
  const float* bt = (const float*)d_in[7];
  const float* Wb = (const float*)d_in[8];
  float* out = (float*)d_out;
  float* ws = (float*)d_ws;

  float* dp = ws + WS_D;
  float* rm = ws + WS_RM;
  float* riz = ws + WS_RIZ;
  float* rmt = ws + WS_RMT;
  float* rzt = ws + WS_RZT;
  float* w_g = ws + WS_W;
  int* cnts = (int*)(ws + WS_CNT);
  unsigned short* wtT = (unsigned short*)(ws + WS_WT);
  unsigned short* thb = (unsigned short*)(ws + WS_THB);
  unsigned short* dWb = (unsigned short*)(ws + WS_DWB);

  count_kernel<<<B_, 256, 0, stream>>>(dmask, tmask, cnts);
  hipMemsetAsync(w_g, 0, (size_t)(B_ * H_ * N_) * sizeof(float), stream);
  hipMemsetAsync(out, 0, (size_t)out_size * sizeof(float), stream);
  transpose_bf16_kernel<<<dim3(HID_ / 32, TD_ / 32), 256, 0, stream>>>(Wt, wtT, TD_, HID_);
  gemm_t_mfma_kernel<<<(HID_ / 128) * ((B_ * L_) / 128), 256, 0, stream>>>(
      tseq, wtT, bt, thb, B_ * L_, TD_);
  gemm_bias_kernel<<<dim3(HID_ / 128, (B_ * N_) / 128), 256, 0, stream>>>(
      drug, Wd, bd, dp, B_ * N_, DD_, HID_);
  dw_kernel<<<B_ * H_, 256, 0, stream>>>(dp, Wb, dWb);
  attn_stats_kernel<<<B_ * H_ * 16, 256, 0, stream>>>(thb, dWb, cnts, w_g, rmt, rzt);
  attn_combine_kernel<<<B_ * H_, 256, 0, stream>>>(rmt, rzt, w_g, dp, cnts, rm, riz, out);
  attn_v_kernel<<<B_ * H_ * 16, 256, 0, stream>>>(thb, dWb, cnts, rm, riz, out);
}

// Round 5
// 472.135 us; speedup vs baseline: 2.5242x; 1.0305x over previous
//
#include <hip/hip_runtime.h>
#include <hip/hip_bf16.h>
#include <math.h>

#define B_ 32
#define N_ 128
#define L_ 1024
#define DD_ 256
#define TD_ 1280
#define HID_ 512
#define H_ 8
#define HD_ 64

// ws layout (float offsets)
#define WS_D    0
#define WS_RM   (WS_D   + 2097152)
#define WS_RIZ  (WS_RM  + 32768)
#define WS_RMT  (WS_RIZ + 32768)
#define WS_RZT  (WS_RMT + 524288)
#define WS_RWT  (WS_RZT + 524288)
#define WS_CNT  (WS_RWT + 524288)
#define WS_WT   (WS_CNT + 64)
#define WS_THB  (WS_WT  + 327680)
#define WS_DWB  (WS_THB + 8388608)
#define WS_ABF  (WS_DWB + 1048576)

using bf16x8 = __attribute__((ext_vector_type(8))) short;
using floatx4 = __attribute__((ext_vector_type(4))) float;

static __device__ __forceinline__ unsigned short f2bf(float f) {
  unsigned int u = __float_as_uint(f);
  unsigned int r = (u + 0x7FFFu + ((u >> 16) & 1u)) >> 16;
  return (unsigned short)r;
}
static __device__ __forceinline__ float bf2f(unsigned short s) {
  return __uint_as_float(((unsigned int)s) << 16);
}
// async global->LDS DMA, 16 B per lane; LDS dest = wave-uniform base + lane*16.
static __device__ __forceinline__ void gload16(const void* g, void* l) {
  __builtin_amdgcn_global_load_lds(
      (const __attribute__((address_space(1))) void*)g,
      (__attribute__((address_space(3))) void*)l, 16, 0, 0);
}

// ---------------------------------------------------------------------------
// K0: per-batch valid counts (detect int32 vs packed-bool at runtime).
// ---------------------------------------------------------------------------
__global__ __launch_bounds__(256) void count_kernel(const int* __restrict__ dmask,
                                                    const int* __restrict__ tmask,
                                                    int* __restrict__ cnts) {
  __shared__ int red[256];
  const int b = blockIdx.x, tid = threadIdx.x;
  const bool dint = (dmask[0] == 1);
  const bool tint = (tmask[0] == 1);
  int s = 0;
  if (dint) {
    for (int i = tid; i < N_; i += 256) s += (dmask[(size_t)b*N_ + i] != 0);
  } else {
    const unsigned char* p = (const unsigned char*)dmask;
    for (int i = tid; i < N_; i += 256) s += (p[(size_t)b*N_ + i] != 0);
  }
  red[tid] = s; __syncthreads();
  for (int off = 128; off > 0; off >>= 1) { if (tid < off) red[tid] += red[tid+off]; __syncthreads(); }
  if (tid == 0) cnts[b*2] = red[0];
  __syncthreads();
  s = 0;
  if (tint) {
    for (int i = tid; i < L_; i += 256) s += (tmask[(size_t)b*L_ + i] != 0);
  } else {
    const unsigned char* p = (const unsigned char*)tmask;
    for (int i = tid; i < L_; i += 256) s += (p[(size_t)b*L_ + i] != 0);
  }
  red[tid] = s; __syncthreads();
  for (int off = 128; off > 0; off >>= 1) { if (tid < off) red[tid] += red[tid+off]; __syncthreads(); }
  if (tid == 0) cnts[b*2+1] = red[0];
}

// ---------------------------------------------------------------------------
// K0a: A fp32 -> bf16 (pure BW pass; removes in-loop f2bf from the GEMM).
// ---------------------------------------------------------------------------
__global__ __launch_bounds__(256) void a2bf_kernel(const float* __restrict__ A,
                                                   unsigned short* __restrict__ Abf,
                                                   long n) {
  long i = ((long)blockIdx.x * 256 + threadIdx.x) * 8;
  const long stride = (long)gridDim.x * 256 * 8;
  for (; i < n; i += stride) {
    float4 x = *(const float4*)(A + i);
    float4 y = *(const float4*)(A + i + 4);
    union { unsigned short s[8]; uint4 u; } p;
    p.s[0] = f2bf(x.x); p.s[1] = f2bf(x.y); p.s[2] = f2bf(x.z); p.s[3] = f2bf(x.w);
    p.s[4] = f2bf(y.x); p.s[5] = f2bf(y.y); p.s[6] = f2bf(y.z); p.s[7] = f2bf(y.w);
    *(uint4*)(Abf + i) = p.u;
  }
}

// ---------------------------------------------------------------------------
// K0b: W (KxN fp32) -> WT (NxK bf16), 32x32 LDS tiles.
// ---------------------------------------------------------------------------
__global__ __launch_bounds__(256) void transpose_bf16_kernel(
    const float* __restrict__ W, unsigned short* __restrict__ WT, int K, int Nd) {
  __shared__ float tile[32][33];
  const int tid = threadIdx.x;
  const int n0 = blockIdx.x * 32, k0 = blockIdx.y * 32;
  const int c = tid & 31, r0 = tid >> 5;
#pragma unroll
  for (int i = 0; i < 4; i++) {
    const int r = r0 + i * 8;
    tile[c][r] = W[(size_t)(k0 + r) * Nd + n0 + c];
  }
  __syncthreads();
#pragma unroll
  for (int i = 0; i < 4; i++) {
    const int r = r0 + i * 8;
    WT[(size_t)(n0 + r) * K + k0 + c] = f2bf(tile[r][c]);
  }
}

// ---------------------------------------------------------------------------
// K1: t-projection, m97-style: both operands bf16, staged via
// global_load_lds (16 B/lane DMA, no VGPR round-trip). BK=64 (2 k-groups of
// 32). Source-address swizzle: kgroup slot i holds (r=i>>2, c=(i&3)^((r>>1)&3))
// so the MFMA ds_read_b128 at slot row*4+(quad^((row>>1)&3)) is bank-conflict-
// free (2-way max). XCD-swizzled 1D grid as in round 4.
// ---------------------------------------------------------------------------
__global__ __launch_bounds__(256) void gemm_t_mfma_kernel(
    const unsigned short* __restrict__ Abf, const unsigned short* __restrict__ WT,
    const float* __restrict__ bias, unsigned short* __restrict__ thb, int K) {
  __shared__ __align__(16) unsigned short As[8192];   // 2 kgroups x 512 slots x 8
  __shared__ __align__(16) unsigned short Bs[8192];
  const int tid = threadIdx.x;
  const int lin = blockIdx.x;
  const int xcd = lin & 7, sq = lin >> 3;
  const int n_t = sq & 3, m_t = (sq >> 2) + xcd * 32;
  const int m0 = m_t * 128, n0 = n_t * 128;
  const int lane = tid & 63, wave = tid >> 6;
  const int wm = wave & 1, wn = wave >> 1;
  const int quad = lane >> 4, lrow = lane & 15;

  floatx4 acc[4][4];
#pragma unroll
  for (int i = 0; i < 4; i++)
#pragma unroll
    for (int j = 0; j < 4; j++) acc[i][j] = (floatx4){0.f, 0.f, 0.f, 0.f};

  // precompute staging source offsets (two calls x two kgroups per operand)
  int srcoff[2][2];   // [call][g] element offset within row-block
#pragma unroll
  for (int call = 0; call < 2; call++) {
    const int i = call * 256 + tid;
    const int r = i >> 2;
    const int c = (i & 3) ^ ((r >> 1) & 3);
#pragma unroll
    for (int g = 0; g < 2; g++) srcoff[call][g] = r * K + g * 32 + c * 8;
  }
  const unsigned short* Abase = Abf + (size_t)m0 * K;
  const unsigned short* Bbase = WT + (size_t)n0 * K;

  for (int k0 = 0; k0 < K; k0 += 64) {
    __syncthreads();
#pragma unroll
    for (int g = 0; g < 2; g++) {
#pragma unroll
      for (int call = 0; call < 2; call++) {
        const int dst = g * 4096 + (call * 256 + wave * 64) * 8;
        gload16(Abase + k0 + srcoff[call][g], &As[dst]);
        gload16(Bbase + k0 + srcoff[call][g], &Bs[dst]);
      }
    }
    __syncthreads();   // compiler emits vmcnt(0) drain before barrier
#pragma unroll
    for (int g = 0; g < 2; g++) {
      bf16x8 bfr[4];
#pragma unroll
      for (int j = 0; j < 4; j++) {
        const int br = wn * 64 + j * 16 + lrow;
        bfr[j] = *(const bf16x8*)&Bs[g * 4096 + (br * 4 + (quad ^ ((br >> 1) & 3))) * 8];
      }
#pragma unroll
      for (int i = 0; i < 4; i++) {
        const int ar = wm * 64 + i * 16 + lrow;
        bf16x8 afr = *(const bf16x8*)&As[g * 4096 + (ar * 4 + (quad ^ ((ar >> 1) & 3))) * 8];
#pragma unroll
        for (int j = 0; j < 4; j++)
          acc[i][j] = __builtin_amdgcn_mfma_f32_16x16x32_bf16(afr, bfr[j], acc[i][j], 0, 0, 0);
      }
    }
  }

  float bj[4];
#pragma unroll
  for (int j = 0; j < 4; j++) bj[j] = bias[n0 + wn * 64 + j * 16 + lrow];
#pragma unroll
  for (int i = 0; i < 4; i++) {
#pragma unroll
    for (int j = 0; j < 4; j++) {
      const int gcol = n0 + wn * 64 + j * 16 + lrow;
      const int hh = gcol >> 6, e = gcol & 63;
#pragma unroll
      for (int r = 0; r < 4; r++) {
        const int grow = m0 + wm * 64 + i * 16 + quad * 4 + r;
        const int bb = grow >> 10, l = grow & 1023;
        thb[(((size_t)bb * H_ + hh) * L_ + l) * HD_ + e] = f2bf(acc[i][j][r] + bj[j]);
      }
    }
  }
}

// ---------------------------------------------------------------------------
// K2: fp32 GEMM for the small d-projection (keeps dproj exact for ctx_t).
// ---------------------------------------------------------------------------
__global__ __launch_bounds__(256) void gemm_bias_kernel(
    const float* __restrict__ A, const float* __restrict__ W,
    const float* __restrict__ bias, float* __restrict__ C,
    int M, int K, int Nd) {
  __shared__ float As[8][132];
  __shared__ float Bs[8][132];
  const int tid = threadIdx.x;
  const int m0 = blockIdx.y * 128, n0 = blockIdx.x * 128;
  const int lr = tid >> 1, lc = (tid & 1) * 4;
  const int wr = tid >> 5, wc = (tid & 31) * 4;
  const int tm = (tid >> 4) * 4, tn = (tid & 15) * 4;

  float acc[2][2][4][4];
#pragma unroll
  for (int a = 0; a < 2; a++)
#pragma unroll
    for (int bq = 0; bq < 2; bq++)
#pragma unroll
      for (int i = 0; i < 4; i++)
#pragma unroll
        for (int j = 0; j < 4; j++) acc[a][bq][i][j] = 0.f;

  const float* Aptr = A + (size_t)(m0 + lr) * K + lc;
  const float* Wptr = W + (size_t)wr * Nd + n0 + wc;

  for (int k0 = 0; k0 < K; k0 += 8) {
    float4 a4 = *(const float4*)(Aptr + k0);
    float4 w4 = *(const float4*)(Wptr + (size_t)k0 * Nd);
    __syncthreads();
    As[lc+0][lr] = a4.x; As[lc+1][lr] = a4.y; As[lc+2][lr] = a4.z; As[lc+3][lr] = a4.w;
    *(float4*)&Bs[wr][wc] = w4;
    __syncthreads();
#pragma unroll
    for (int kk = 0; kk < 8; kk++) {
      float4 a0 = *(const float4*)&As[kk][tm];
      float4 a1 = *(const float4*)&As[kk][tm + 64];
      float4 b0 = *(const float4*)&Bs[kk][tn];
      float4 b1 = *(const float4*)&Bs[kk][tn + 64];
      const float av0[4] = {a0.x, a0.y, a0.z, a0.w};
      const float av1[4] = {a1.x, a1.y, a1.z, a1.w};
      const float bv0[4] = {b0.x, b0.y, b0.z, b0.w};
      const float bv1[4] = {b1.x, b1.y, b1.z, b1.w};
#pragma unroll
      for (int i = 0; i < 4; i++)
#pragma unroll
        for (int j = 0; j < 4; j++) {
          acc[0][0][i][j] += av0[i] * bv0[j];
          acc[0][1][i][j] += av0[i] * bv1[j];
          acc[1][0][i][j] += av1[i] * bv0[j];
          acc[1][1][i][j] += av1[i] * bv1[j];
        }
    }
  }
  float4 bias0 = *(const float4*)&bias[n0 + tn];
  float4 bias1 = *(const float4*)&bias[n0 + tn + 64];
  const float bb0[4] = {bias0.x, bias0.y, bias0.z, bias0.w};
  const float bb1[4] = {bias1.x, bias1.y, bias1.z, bias1.w};
#pragma unroll
  for (int mh = 0; mh < 2; mh++)
#pragma unroll
    for (int i = 0; i < 4; i++) {
      const int row = m0 + mh * 64 + tm + i;
      float* cp = C + (size_t)row * Nd + n0;
      float4 o0, o1;
      o0.x = acc[mh][0][i][0] + bb0[0]; o0.y = acc[mh][0][i][1] + bb0[1];
      o0.z = acc[mh][0][i][2] + bb0[2]; o0.w = acc[mh][0][i][3] + bb0[3];
      o1.x = acc[mh][1][i][0] + bb1[0]; o1.y = acc[mh][1][i][1] + bb1[1];
      o1.z = acc[mh][1][i][2] + bb1[2]; o1.w = acc[mh][1][i][3] + bb1[3];
      *(float4*)(cp + tn) = o0;
      *(float4*)(cp + tn + 64) = o1;
    }
}

// ---------------------------------------------------------------------------
// K3: dWb[b][h][n][e] = (dh @ Wb[h]) in bf16. grid = 256 (hb = b*8+h).
// ---------------------------------------------------------------------------
__global__ __launch_bounds__(256) void dw_kernel(
    const float* __restrict__ dproj, const float* __restrict__ Wb,
    unsigned short* __restrict__ dWb) {
  __shared__ float wb_s[64 * 64];
  const int tid = threadIdx.x;
  const int hb = blockIdx.x, b = hb >> 3, h = hb & 7;
  for (int i = tid; i < 4096; i += 256) wb_s[i] = Wb[(size_t)h * 4096 + i];
  __syncthreads();
  const int n = tid >> 1, half = tid & 1;
  float acc[32];
#pragma unroll
  for (int e = 0; e < 32; e++) acc[e] = 0.f;
  const float* dpr = dproj + ((size_t)(b * N_ + n)) * HID_ + h * HD_;
  for (int k = 0; k < 64; k++) {
    const float a = dpr[k];
    const float* wr = &wb_s[k * 64 + half * 32];
#pragma unroll
    for (int e = 0; e < 32; e++) acc[e] += a * wr[e];
  }
  unsigned short* outp = dWb + ((size_t)hb * N_ + n) * HD_ + half * 32;
#pragma unroll
  for (int e = 0; e < 32; e++) outp[e] = f2bf(acc[e]);
}

// ---------------------------------------------------------------------------
// S-tile (128n x 64l) via MFMA, operands from global bf16 head-major arrays;
// masked fp32 S to LDS (stride 69: conflict-light on row and column walks).
// ---------------------------------------------------------------------------
__device__ __forceinline__ void mfma_S_tile(
    const unsigned short* __restrict__ thp, const unsigned short* __restrict__ dwp,
    float* __restrict__ S_s, int ncnt, int lv, int tid) {
  const int lane = tid & 63, wave = tid >> 6;
  const int quad = lane >> 4, lr = lane & 15;
  const int noff = (wave & 1) * 64, loff = (wave >> 1) * 32;

  floatx4 acc[4][2];
#pragma unroll
  for (int i = 0; i < 4; i++)
#pragma unroll
    for (int j = 0; j < 2; j++) acc[i][j] = (floatx4){0.f, 0.f, 0.f, 0.f};

#pragma unroll
  for (int kc = 0; kc < 2; kc++) {
    bf16x8 bfr[2];
#pragma unroll
    for (int j = 0; j < 2; j++)
      bfr[j] = *(const bf16x8*)&thp[(size_t)(loff + j * 16 + lr) * HD_ + kc * 32 + quad * 8];
#pragma unroll
    for (int i = 0; i < 4; i++) {
      bf16x8 afr = *(const bf16x8*)&dwp[(size_t)(noff + i * 16 + lr) * HD_ + kc * 32 + quad * 8];
#pragma unroll
      for (int j = 0; j < 2; j++)
        acc[i][j] = __builtin_amdgcn_mfma_f32_16x16x32_bf16(afr, bfr[j], acc[i][j], 0, 0, 0);
    }
  }
#pragma unroll
  for (int i = 0; i < 4; i++)
#pragma unroll
    for (int j = 0; j < 2; j++)
#pragma unroll
      for (int r = 0; r < 4; r++) {
        const int n = noff + i * 16 + quad * 4 + r;
        const int li = loff + j * 16 + lr;
        const bool ok = (n < ncnt) && (li < lv);
        S_s[n * 69 + li] = ok ? acc[i][j][r] : -1e9f;
      }
}

// ---------------------------------------------------------------------------
// K4: per (hb, lt): S tile -> column softmax (complete per tile); per-tile
// row stats (m_t, z_t) and per-tile w partial (no atomics). grid = 256*16.
// ---------------------------------------------------------------------------
__global__ __launch_bounds__(256, 4) void attn_stats_kernel(
    const unsigned short* __restrict__ thb, const unsigned short* __restrict__ dWb,
    const int* __restrict__ cnts, float* __restrict__ rwt,
    float* __restrict__ rmt, float* __restrict__ rzt) {
  __shared__ float S_s[128 * 69];
  __shared__ float red[256];
  __shared__ float zb_s[256], wb_s[256];
  __shared__ float cm_s[64], ics_s[64];
  const int tid = threadIdx.x;
  const int hb = blockIdx.x >> 4, lt = blockIdx.x & 15;
  const int b = hb >> 3;
  const int ncnt = cnts[b * 2], lcnt = cnts[b * 2 + 1];
  const int l0g = lt * 64;
  if (l0g >= lcnt) return;
  const int lv = min(64, lcnt - l0g);

  mfma_S_tile(thb + ((size_t)hb * L_ + l0g) * HD_, dWb + (size_t)hb * N_ * HD_,
              S_s, ncnt, lv, tid);
  __syncthreads();

  {  // column max partials (over n)
    const int l = tid & 63, q = tid >> 6;
    float pm = -INFINITY;
    for (int n = q * 32; n < q * 32 + 32; n++) pm = fmaxf(pm, S_s[n * 69 + l]);
    red[tid] = pm;
  }
  __syncthreads();
  if (tid < 64)
    cm_s[tid] = fmaxf(fmaxf(red[tid], red[tid + 64]), fmaxf(red[tid + 128], red[tid + 192]));
  __syncthreads();
  {  // column expsum partials
    const int l = tid & 63, q = tid >> 6;
    const float cm = cm_s[l];
    float ps = 0.f;
    for (int n = q * 32; n < q * 32 + 32; n++) ps += __expf(S_s[n * 69 + l] - cm);
    red[tid] = ps;
  }
  __syncthreads();
  if (tid < 64)
    ics_s[tid] = 1.f / (red[tid] + red[tid + 64] + red[tid + 128] + red[tid + 192]);
  __syncthreads();
  {  // row pass, split across halves: n = tid&127, half covers 32 l's
    const int n = tid & 127, half = tid >> 7;
    const float* Sr = &S_s[n * 69];
    const int lb = half * 32, le = min(lb + 32, lv);
    float tmax = -INFINITY;
    for (int l = lb; l < le; l++) tmax = fmaxf(tmax, Sr[l]);
    red[tid] = tmax;
    __syncthreads();
    const float tm = fmaxf(red[n], red[n + 128]);
    float z = 0.f, w = 0.f;
    for (int l = lb; l < le; l++) {
      const float s = Sr[l];
      z += __expf(s - tm);
      w += __expf(s - cm_s[l]) * ics_s[l];
    }
    zb_s[tid] = z; wb_s[tid] = w;
    __syncthreads();
    if (tid < 128) {
      const size_t o = ((size_t)hb * 16 + lt) * 128 + tid;
      rmt[o] = tm;
      rzt[o] = zb_s[tid] + zb_s[tid + 128];
      rwt[o] = wb_s[tid] + wb_s[tid + 128];
    }
  }
}

// ---------------------------------------------------------------------------
// K5: combine per-tile row stats -> (m, 1/Z) and w; finalize ctx_t. grid=256.
// ---------------------------------------------------------------------------
__global__ __launch_bounds__(256) void attn_combine_kernel(
    const float* __restrict__ rmt, const float* __restrict__ rzt,
    const float* __restrict__ rwt, const float* __restrict__ dproj,
    const int* __restrict__ cnts, float* __restrict__ rm_g,
    float* __restrict__ riz_g, float* __restrict__ outp) {
  __shared__ float red[256];
  __shared__ float w_s[128];
  const int tid = threadIdx.x;
  const int hb = blockIdx.x, b = hb >> 3, h = hb & 7;
  const int ncnt = cnts[b * 2], lcnt = cnts[b * 2 + 1];
  const int ntl = (lcnt + 63) >> 6;
  if (tid < 128) {
    const int n = tid;
    float m = -INFINITY;
    for (int t = 0; t < ntl; t++)
      m = fmaxf(m, rmt[((size_t)hb * 16 + t) * 128 + n]);
    float Z = 0.f, w = 0.f;
    for (int t = 0; t < ntl; t++) {
      const size_t o = ((size_t)hb * 16 + t) * 128 + n;
      Z += rzt[o] * __expf(rmt[o] - m);
      w += rwt[o];
    }
    rm_g[hb * 128 + n] = m;
    riz_g[hb * 128 + n] = (n < ncnt) ? 1.f / Z : 0.f;
    w_s[n] = (n < ncnt) ? w : 0.f;
  }
  __syncthreads();
  const int e = tid & 63, q = tid >> 6;
  float p = 0.f;
  const int nb = q * 32, ne = min(nb + 32, ncnt);
  for (int n = nb; n < ne; n++)
    p += w_s[n] * dproj[((size_t)(b * N_ + n)) * HID_ + h * HD_ + e];
  red[tid] = p;
  __syncthreads();
  if (tid < 64) {
    const float s = red[tid] + red[tid + 64] + red[tid + 128] + red[tid + 192];
    outp[(size_t)b * (2 * HID_) + HID_ + h * HD_ + tid] = s / (float)lcnt;
  }
}

// ---------------------------------------------------------------------------
// K6: recompute S tile; v[l] = sum_n exp(S-m[n])/Z[n]; fused ctx_d partial
// accumulation (atomicAdd into zero-initialized out). grid = 256*16.
// ---------------------------------------------------------------------------
__global__ __launch_bounds__(256, 4) void attn_v_kernel(
    const unsigned short* __restrict__ thb, const unsigned short* __restrict__ dWb,
    const int* __restrict__ cnts, const float* __restrict__ rm_g,
    const float* __restrict__ riz_g, float* __restrict__ outp) {
  __shared__ float S_s[128 * 69];
  __shared__ float red[256];
  __shared__ float rm_s[128], riz_s[128], v_s[64];
  const int tid = threadIdx.x;
  const int hb = blockIdx.x >> 4, lt = blockIdx.x & 15;
  const int b = hb >> 3, h = hb & 7;
  const int ncnt = cnts[b * 2], lcnt = cnts[b * 2 + 1];
  const int l0g = lt * 64;
  if (l0g >= lcnt) return;
  const int lv = min(64, lcnt - l0g);

  if (tid < 128) {
    rm_s[tid] = rm_g[hb * 128 + tid];
    riz_s[tid] = riz_g[hb * 128 + tid];
  }
  const unsigned short* thp = thb + ((size_t)hb * L_ + l0g) * HD_;
  mfma_S_tile(thp, dWb + (size_t)hb * N_ * HD_, S_s, ncnt, lv, tid);
  __syncthreads();

  {
    const int l = tid & 63, q = tid >> 6;
    float vp = 0.f;
    for (int n = q * 32; n < q * 32 + 32; n++)
      vp += __expf(S_s[n * 69 + l] - rm_s[n]) * riz_s[n];
    red[tid] = vp;
  }
  __syncthreads();
  const float incnt = 1.f / (float)ncnt;
  if (tid < 64) {
    const float v = (tid < lv)
        ? (red[tid] + red[tid + 64] + red[tid + 128] + red[tid + 192]) * incnt
        : 0.f;
    v_s[tid] = v;
  }
  __syncthreads();
  {  // fused ctx_d partial: sum_{l in tile} v[l] * th[l][e]
    const int e = tid & 63, q = tid >> 6;
    float p = 0.f;
    for (int l = q * 16; l < q * 16 + 16; l++)
      p += v_s[l] * bf2f(thp[(size_t)l * HD_ + e]);
    red[tid] = p;
  }
  __syncthreads();
  if (tid < 64) {
    const float s = red[tid] + red[tid + 64] + red[tid + 128] + red[tid + 192];
    if (s != 0.f)
      atomicAdd(&outp[(size_t)b * (2 * HID_) + h * HD_ + tid], s);
  }
}

// ---------------------------------------------------------------------------
extern "C" void kernel_launch(void* const* d_in, const int* in_sizes, int n_in,
                              void* d_out, int out_size, void* d_ws, size_t ws_size,
                              hipStream_t stream) {
  const float* drug = (const float*)d_in[0];
  const int* dmask = (const int*)d_in[1];
  const float* tseq = (const float*)d_in[2];
  const int* tmask = (const int*)d_in[3];
  const float* Wd = (const float*)d_in[4];
  const float* bd = (const float*)d_in[5];
  const float* Wt = (const float*)d_in[6];
  const float* bt = (const float*)d_in[7];
  const float* Wb = (const float*)d_in[8];
  float* out = (float*)d_out;
  float* ws = (float*)d_ws;

  float* dp = ws + WS_D;
  float* rm = ws + WS_RM;
  float* riz = ws + WS_RIZ;
  float* rmt = ws + WS_RMT;
  float* rzt = ws + WS_RZT;
  float* rwt = ws + WS_RWT;
  int* cnts = (int*)(ws + WS_CNT);
  unsigned short* wtT = (unsigned short*)(ws + WS_WT);
  unsigned short* thb = (unsigned short*)(ws + WS_THB);
  unsigned short* dWb = (unsigned short*)(ws + WS_DWB);
  unsigned short* abf = (unsigned short*)(ws + WS_ABF);

  count_kernel<<<B_, 256, 0, stream>>>(dmask, tmask, cnts);
  hipMemsetAsync(out, 0, (size_t)out_size * sizeof(float), stream);
  a2bf_kernel<<<1024, 256, 0, stream>>>(tseq, abf, (long)B_ * L_ * TD_);
  transpose_bf16_kernel<<<dim3(HID_ / 32, TD_ / 32), 256, 0, stream>>>(Wt, wtT, TD_, HID_);
  gemm_t_mfma_kernel<<<(HID_ / 128) * ((B_ * L_) / 128), 256, 0, stream>>>(
      abf, wtT, bt, thb, TD_);
  gemm_bias_kernel<<<dim3(HID_ / 128, (B_ * N_) / 128), 256, 0, stream>>>(
      drug, Wd, bd, dp, B_ * N_, DD_, HID_);
  dw_kernel<<<B_ * H_, 256, 0, stream>>>(dp, Wb, dWb);
  attn_stats_kernel<<<B_ * H_ * 16, 256, 0, stream>>>(thb, dWb, cnts, rwt, rmt, rzt);
  attn_combine_kernel<<<B_ * H_, 256, 0, stream>>>(rmt, rzt, rwt, dp, cnts, rm, riz, out);
  attn_v_kernel<<<B_ * H_ * 16, 256, 0, stream>>>(thb, dWb, cnts, rm, riz, out);
}